// Round 1
// baseline (2307.726 us; speedup 1.0000x reference)
//
#include <hip/hip_runtime.h>

// ---------------------------------------------------------------------------
// Local attention block, B=16 C=512 N=2048, fp32 baseline (round 1).
// Pipeline:
//   K1 k_proj   : xk[b]=wqk@x[b] (128xN), xv[b]=wv@x[b]+bv (512xN)
//   K2 k_stats  : row max / sumexp of energy = xk^T xk (flash pass 1)
//   K3 k_attn_pv: recompute energy tiles, p=exp(e-max)*invS, u = x - xv@p
//   K4 k_trans  : t = wt@u + bt  (+ atomic BN partial sums)
//   K5 k_bnfin  : per-channel scale/shift from BN stats
//   K6 k_out    : out = x + relu(t*scale+shift)
// ws layout (floats): xk | xv(->t) | u | rowmax | rowinv | bns | bnq | sc | sh
// ws requirement ~152 MB.
// ---------------------------------------------------------------------------

#define BB 16
#define CC 512
#define C4 128
#define NN 2048

static const size_t XK_OFF   = 0;
static const size_t XV_OFF   = XK_OFF + (size_t)BB * C4 * NN;   //  4,194,304
static const size_t U_OFF    = XV_OFF + (size_t)BB * CC * NN;   // 20,971,520
static const size_t RMAX_OFF = U_OFF  + (size_t)BB * CC * NN;   // 37,748,736
static const size_t RINV_OFF = RMAX_OFF + (size_t)BB * NN;
static const size_t BNS_OFF  = RINV_OFF + (size_t)BB * NN;
static const size_t BNQ_OFF  = BNS_OFF + CC;
static const size_t SC_OFF   = BNQ_OFF + CC;
static const size_t SH_OFF   = SC_OFF + CC;

// ---------------------------------------------------------------------------
// K1: fused projection GEMM. M=640 (rows 0..127 -> xk, 128..639 -> xv+bias),
// K=512, N=2048, per batch. 64x64 tile, 256 threads, 4x4 per thread.
// ---------------------------------------------------------------------------
__global__ __launch_bounds__(256) void k_proj(
    const float* __restrict__ x, const float* __restrict__ wqk,
    const float* __restrict__ wv, const float* __restrict__ bv,
    float* __restrict__ xk, float* __restrict__ xvb)
{
    __shared__ float As[64][20];   // row stride 80B -> 16B aligned, no 8-way bank conflict
    __shared__ float Bs[16][68];   // row stride 272B -> 16B aligned
    const int b = blockIdx.z, by = blockIdx.y, bx = blockIdx.x;
    const int tid = threadIdx.x;
    const int ty = tid >> 4, tx = tid & 15;
    const int ar = tid >> 2, ak = (tid & 3) << 2;
    const int br = tid >> 4, bc = (tid & 15) << 2;
    const int rowg = by * 64 + ar;
    const float* aptr = (rowg < C4) ? (wqk + (size_t)rowg * CC)
                                    : (wv + (size_t)(rowg - C4) * CC);
    const float* xb = x + (size_t)b * CC * NN;
    float acc[4][4] = {};
    for (int k0 = 0; k0 < CC; k0 += 16) {
        const float4 av  = *(const float4*)(aptr + k0 + ak);
        const float4 bg  = *(const float4*)(xb + (size_t)(k0 + br) * NN + bx * 64 + bc);
        __syncthreads();
        *(float4*)&As[ar][ak] = av;
        *(float4*)&Bs[br][bc] = bg;
        __syncthreads();
#pragma unroll
        for (int k = 0; k < 16; ++k) {
            const float4 bq = *(const float4*)&Bs[k][tx << 2];
            const float a0 = As[ty * 4 + 0][k];
            const float a1 = As[ty * 4 + 1][k];
            const float a2 = As[ty * 4 + 2][k];
            const float a3 = As[ty * 4 + 3][k];
            acc[0][0] += a0 * bq.x; acc[0][1] += a0 * bq.y; acc[0][2] += a0 * bq.z; acc[0][3] += a0 * bq.w;
            acc[1][0] += a1 * bq.x; acc[1][1] += a1 * bq.y; acc[1][2] += a1 * bq.z; acc[1][3] += a1 * bq.w;
            acc[2][0] += a2 * bq.x; acc[2][1] += a2 * bq.y; acc[2][2] += a2 * bq.z; acc[2][3] += a2 * bq.w;
            acc[3][0] += a3 * bq.x; acc[3][1] += a3 * bq.y; acc[3][2] += a3 * bq.z; acc[3][3] += a3 * bq.w;
        }
    }
    float* outk = xk  + (size_t)b * C4 * NN;
    float* outv = xvb + (size_t)b * CC * NN;
    const int n = bx * 64 + (tx << 2);
#pragma unroll
    for (int i = 0; i < 4; ++i) {
        const int r = by * 64 + ty * 4 + i;
        float4 o;
        o.x = acc[i][0]; o.y = acc[i][1]; o.z = acc[i][2]; o.w = acc[i][3];
        if (r < C4) {
            *(float4*)(outk + (size_t)r * NN + n) = o;
        } else {
            const float bias = bv[r - C4];
            o.x += bias; o.y += bias; o.z += bias; o.w += bias;
            *(float4*)(outv + (size_t)(r - C4) * NN + n) = o;
        }
    }
}

// ---------------------------------------------------------------------------
// K2: flash pass 1 — per-row max and sum(exp) of energy[n,m]=sum_d xk[d,n]xk[d,m].
// Block: 64 rows (i-block) x all 2048 cols, 256 threads (16x16, 4x4 e-tiles).
// ---------------------------------------------------------------------------
__global__ __launch_bounds__(256) void k_stats(
    const float* __restrict__ xk, float* __restrict__ rmax, float* __restrict__ rinv)
{
    __shared__ float xi[128][68];
    __shared__ float xm[128][68];
    __shared__ float redm[64][16];
    __shared__ float reds[64][16];
    const int b = blockIdx.y, ib = blockIdx.x;
    const int tid = threadIdx.x;
    const int ty = tid >> 4, tx = tid & 15;
    const float* xkb = xk + (size_t)b * C4 * NN;
    {   // stage xi = xk[:, ib*64 .. +64]
        const int d = tid >> 1, h = tid & 1;
#pragma unroll
        for (int q = 0; q < 8; ++q) {
            const int col = h * 32 + q * 4;
            *(float4*)&xi[d][col] = *(const float4*)(xkb + (size_t)d * NN + ib * 64 + col);
        }
    }
    float m[4], s[4];
#pragma unroll
    for (int a = 0; a < 4; ++a) { m[a] = -3.0e38f; s[a] = 0.0f; }

    for (int mt = 0; mt < NN / 64; ++mt) {
        __syncthreads();
        {   // stage xm = xk[:, mt*64 .. +64]
            const int d = tid >> 1, h = tid & 1;
#pragma unroll
            for (int q = 0; q < 8; ++q) {
                const int col = h * 32 + q * 4;
                *(float4*)&xm[d][col] = *(const float4*)(xkb + (size_t)d * NN + mt * 64 + col);
            }
        }
        __syncthreads();
        float e[4][4] = {};
        for (int d = 0; d < 128; ++d) {
            const float4 bq = *(const float4*)&xm[d][tx << 2];
            const float a0 = xi[d][ty * 4 + 0];
            const float a1 = xi[d][ty * 4 + 1];
            const float a2 = xi[d][ty * 4 + 2];
            const float a3 = xi[d][ty * 4 + 3];
            e[0][0] += a0 * bq.x; e[0][1] += a0 * bq.y; e[0][2] += a0 * bq.z; e[0][3] += a0 * bq.w;
            e[1][0] += a1 * bq.x; e[1][1] += a1 * bq.y; e[1][2] += a1 * bq.z; e[1][3] += a1 * bq.w;
            e[2][0] += a2 * bq.x; e[2][1] += a2 * bq.y; e[2][2] += a2 * bq.z; e[2][3] += a2 * bq.w;
            e[3][0] += a3 * bq.x; e[3][1] += a3 * bq.y; e[3][2] += a3 * bq.z; e[3][3] += a3 * bq.w;
        }
#pragma unroll
        for (int a = 0; a < 4; ++a) {
            const float vm = fmaxf(fmaxf(e[a][0], e[a][1]), fmaxf(e[a][2], e[a][3]));
            const float nm = fmaxf(m[a], vm);
            const float add = __expf(e[a][0] - nm) + __expf(e[a][1] - nm) +
                              __expf(e[a][2] - nm) + __expf(e[a][3] - nm);
            s[a] = s[a] * __expf(m[a] - nm) + add;
            m[a] = nm;
        }
    }
    __syncthreads();
#pragma unroll
    for (int a = 0; a < 4; ++a) {
        redm[ty * 4 + a][tx] = m[a];
        reds[ty * 4 + a][tx] = s[a];
    }
    __syncthreads();
    if (tid < 64) {
        const int r = tid;
        float M = -3.0e38f;
#pragma unroll
        for (int t = 0; t < 16; ++t) M = fmaxf(M, redm[r][t]);
        float S = 0.0f;
#pragma unroll
        for (int t = 0; t < 16; ++t) S += reds[r][t] * __expf(redm[r][t] - M);
        rmax[(size_t)b * NN + ib * 64 + r] = M;
        // softmax row-sum is 1 (+-1e-7); fold the L1 renorm 1/(1e-9+1) into invS
        rinv[(size_t)b * NN + ib * 64 + r] = 1.0f / (S * (1.0f + 1e-9f));
    }
}

// ---------------------------------------------------------------------------
// K3: flash pass 2 — u[b,:,m] = x[b,:,m] - sum_n xv[b,:,n] * p[n,m],
// p[n,m] = exp(e[n,m]-rowmax[n]) * rowinv[n].  Block: one m-block (64 cols),
// ALL 512 channels, 512 threads. n-tiles of 32.
// ---------------------------------------------------------------------------
__global__ __launch_bounds__(512) void k_attn_pv(
    const float* __restrict__ xk, const float* __restrict__ xv,
    const float* __restrict__ x, const float* __restrict__ rmax,
    const float* __restrict__ rinv, float* __restrict__ u)
{
    __shared__ float xm[128][68];    // xk[:, m-block]      34.8 KB
    __shared__ float xn[128][36];    // xk[:, n-tile]       18.4 KB
    __shared__ float xvs[512][36];   // xv[:, n-tile]       73.7 KB
    __shared__ float p[32][68];      // attention tile       8.7 KB
    const int b = blockIdx.z, mb = blockIdx.x;
    const int tid = threadIdx.x;
    const int tx = tid & 15;         // m quarter (4 cols)
    const int tg = tid >> 4;         // 0..31
    const int m0 = mb * 64;
    const float* xkb = xk + (size_t)b * C4 * NN;
    const float* xvb = xv + (size_t)b * CC * NN;
    {   // stage xm (persistent)
        const int d = tid >> 2, q = tid & 3;
#pragma unroll
        for (int w = 0; w < 4; ++w) {
            const int col = q * 16 + w * 4;
            *(float4*)&xm[d][col] = *(const float4*)(xkb + (size_t)d * NN + m0 + col);
        }
    }
    float acc[16][4] = {};           // c = tg + i*32, m = m0 + tx*4 + j
    for (int nt = 0; nt < NN / 32; ++nt) {
        const int n0 = nt * 32;
        __syncthreads();             // prev PV done (and first-iter xm visible below)
        {   // stage xn: 128x32
            const int d = tid >> 2, q = tid & 3;
            *(float4*)&xn[d][q * 8]     = *(const float4*)(xkb + (size_t)d * NN + n0 + q * 8);
            *(float4*)&xn[d][q * 8 + 4] = *(const float4*)(xkb + (size_t)d * NN + n0 + q * 8 + 4);
        }
        {   // stage xvs: 512x32, one row per thread
            const float* src = xvb + (size_t)tid * NN + n0;
#pragma unroll
            for (int w = 0; w < 8; ++w)
                *(float4*)&xvs[tid][w * 4] = *(const float4*)(src + w * 4);
        }
        __syncthreads();
        // e-tile: row nn=tg, cols m0+tx*4..+4
        float e0 = 0.f, e1 = 0.f, e2 = 0.f, e3 = 0.f;
        for (int d = 0; d < 128; ++d) {
            const float av = xn[d][tg];
            const float4 bq = *(const float4*)&xm[d][tx << 2];
            e0 += av * bq.x; e1 += av * bq.y; e2 += av * bq.z; e3 += av * bq.w;
        }
        const float rm = rmax[(size_t)b * NN + n0 + tg];
        const float ri = rinv[(size_t)b * NN + n0 + tg];
        float4 pv;
        pv.x = __expf(e0 - rm) * ri;
        pv.y = __expf(e1 - rm) * ri;
        pv.z = __expf(e2 - rm) * ri;
        pv.w = __expf(e3 - rm) * ri;
        *(float4*)&p[tg][tx << 2] = pv;
        __syncthreads();
        // PV accumulate over this n-tile
        for (int nn = 0; nn < 32; ++nn) {
            const float4 pj = *(const float4*)&p[nn][tx << 2];
#pragma unroll
            for (int i = 0; i < 16; ++i) {
                const float v = xvs[tg + i * 32][nn];
                acc[i][0] += v * pj.x; acc[i][1] += v * pj.y;
                acc[i][2] += v * pj.z; acc[i][3] += v * pj.w;
            }
        }
    }
    // u = x - x_r
    const float* xb = x + (size_t)b * CC * NN;
    float* ub = u + (size_t)b * CC * NN;
#pragma unroll
    for (int i = 0; i < 16; ++i) {
        const int c = tg + i * 32;
        const size_t off = (size_t)c * NN + m0 + (tx << 2);
        const float4 xq = *(const float4*)(xb + off);
        float4 o;
        o.x = xq.x - acc[i][0]; o.y = xq.y - acc[i][1];
        o.z = xq.z - acc[i][2]; o.w = xq.w - acc[i][3];
        *(float4*)(ub + off) = o;
    }
}

// ---------------------------------------------------------------------------
// K4: t = wt @ u + bt, plus per-channel BN partial sums (atomics).
// ---------------------------------------------------------------------------
__global__ __launch_bounds__(256) void k_trans(
    const float* __restrict__ wt, const float* __restrict__ bt,
    const float* __restrict__ u, float* __restrict__ t,
    float* __restrict__ bns, float* __restrict__ bnq)
{
    __shared__ float As[64][20];
    __shared__ float Bs[16][68];
    const int b = blockIdx.z, by = blockIdx.y, bx = blockIdx.x;
    const int tid = threadIdx.x;
    const int ty = tid >> 4, tx = tid & 15;
    const int ar = tid >> 2, ak = (tid & 3) << 2;
    const int br = tid >> 4, bc = (tid & 15) << 2;
    const float* aptr = wt + (size_t)(by * 64 + ar) * CC;
    const float* ub = u + (size_t)b * CC * NN;
    float acc[4][4] = {};
    for (int k0 = 0; k0 < CC; k0 += 16) {
        const float4 av = *(const float4*)(aptr + k0 + ak);
        const float4 bg = *(const float4*)(ub + (size_t)(k0 + br) * NN + bx * 64 + bc);
        __syncthreads();
        *(float4*)&As[ar][ak] = av;
        *(float4*)&Bs[br][bc] = bg;
        __syncthreads();
#pragma unroll
        for (int k = 0; k < 16; ++k) {
            const float4 bq = *(const float4*)&Bs[k][tx << 2];
            const float a0 = As[ty * 4 + 0][k];
            const float a1 = As[ty * 4 + 1][k];
            const float a2 = As[ty * 4 + 2][k];
            const float a3 = As[ty * 4 + 3][k];
            acc[0][0] += a0 * bq.x; acc[0][1] += a0 * bq.y; acc[0][2] += a0 * bq.z; acc[0][3] += a0 * bq.w;
            acc[1][0] += a1 * bq.x; acc[1][1] += a1 * bq.y; acc[1][2] += a1 * bq.z; acc[1][3] += a1 * bq.w;
            acc[2][0] += a2 * bq.x; acc[2][1] += a2 * bq.y; acc[2][2] += a2 * bq.z; acc[2][3] += a2 * bq.w;
            acc[3][0] += a3 * bq.x; acc[3][1] += a3 * bq.y; acc[3][2] += a3 * bq.z; acc[3][3] += a3 * bq.w;
        }
    }
    float* tb = t + (size_t)b * CC * NN;
    const int n = bx * 64 + (tx << 2);
#pragma unroll
    for (int i = 0; i < 4; ++i) {
        const int r = by * 64 + ty * 4 + i;
        const float bias = bt[r];
        float4 o;
        o.x = acc[i][0] + bias; o.y = acc[i][1] + bias;
        o.z = acc[i][2] + bias; o.w = acc[i][3] + bias;
        *(float4*)(tb + (size_t)r * NN + n) = o;
        float rs = o.x + o.y + o.z + o.w;
        float rq = o.x * o.x + o.y * o.y + o.z * o.z + o.w * o.w;
#pragma unroll
        for (int off = 1; off < 16; off <<= 1) {
            rs += __shfl_xor(rs, off);
            rq += __shfl_xor(rq, off);
        }
        if (tx == 0) {
            atomicAdd(&bns[r], rs);
            atomicAdd(&bnq[r], rq);
        }
    }
}

// ---------------------------------------------------------------------------
// K5: finalize BN -> per-channel scale/shift
// ---------------------------------------------------------------------------
__global__ void k_bnfin(const float* __restrict__ bns, const float* __restrict__ bnq,
                        const float* __restrict__ gamma, const float* __restrict__ beta,
                        float* __restrict__ scale, float* __restrict__ shift)
{
    const int c = threadIdx.x;
    if (c < CC) {
        const float inv = 1.0f / (float)(BB * NN);
        const float mean = bns[c] * inv;
        const float var = bnq[c] * inv - mean * mean;
        const float sc = gamma[c] * rsqrtf(var + 1e-5f);
        scale[c] = sc;
        shift[c] = beta[c] - mean * sc;
    }
}

// ---------------------------------------------------------------------------
// K6: out = x + relu(t*scale + shift)
// ---------------------------------------------------------------------------
__global__ __launch_bounds__(256) void k_out(
    const float* __restrict__ x, const float* __restrict__ t,
    const float* __restrict__ scale, const float* __restrict__ shift,
    float* __restrict__ out)
{
    const size_t total4 = (size_t)BB * CC * NN / 4;
    for (size_t idx = (size_t)blockIdx.x * blockDim.x + threadIdx.x; idx < total4;
         idx += (size_t)gridDim.x * blockDim.x) {
        const size_t e = idx * 4;
        const int c = (int)((e / NN) % CC);
        const float sc = scale[c], sh = shift[c];
        const float4 xq = ((const float4*)x)[idx];
        const float4 tq = ((const float4*)t)[idx];
        float4 o;
        o.x = xq.x + fmaxf(tq.x * sc + sh, 0.0f);
        o.y = xq.y + fmaxf(tq.y * sc + sh, 0.0f);
        o.z = xq.z + fmaxf(tq.z * sc + sh, 0.0f);
        o.w = xq.w + fmaxf(tq.w * sc + sh, 0.0f);
        ((float4*)out)[idx] = o;
    }
}

// ---------------------------------------------------------------------------
extern "C" void kernel_launch(void* const* d_in, const int* in_sizes, int n_in,
                              void* d_out, int out_size, void* d_ws, size_t ws_size,
                              hipStream_t stream)
{
    const float* x     = (const float*)d_in[0];
    const float* wqk   = (const float*)d_in[1];
    const float* wv    = (const float*)d_in[2];
    const float* bv    = (const float*)d_in[3];
    const float* wt    = (const float*)d_in[4];
    const float* bt    = (const float*)d_in[5];
    const float* gamma = (const float*)d_in[6];
    const float* beta  = (const float*)d_in[7];
    float* ws = (float*)d_ws;

    float* xk   = ws + XK_OFF;
    float* xvb  = ws + XV_OFF;   // later reused as t
    float* ub   = ws + U_OFF;
    float* rmax = ws + RMAX_OFF;
    float* rinv = ws + RINV_OFF;
    float* bns  = ws + BNS_OFF;
    float* bnq  = ws + BNQ_OFF;
    float* sc   = ws + SC_OFF;
    float* sh   = ws + SH_OFF;

    hipMemsetAsync(bns, 0, 2 * CC * sizeof(float), stream);  // bns + bnq contiguous

    k_proj<<<dim3(NN / 64, 10, BB), 256, 0, stream>>>(x, wqk, wv, bv, xk, xvb);
    k_stats<<<dim3(NN / 64, BB), 256, 0, stream>>>(xk, rmax, rinv);
    k_attn_pv<<<dim3(NN / 64, 1, BB), 512, 0, stream>>>(xk, xvb, x, rmax, rinv, ub);
    k_trans<<<dim3(NN / 64, 8, BB), 256, 0, stream>>>(wt, bt, ub, xvb, bns, bnq);
    k_bnfin<<<1, 512, 0, stream>>>(bns, bnq, gamma, beta, sc, sh);
    k_out<<<2048, 256, 0, stream>>>(x, xvb, sc, sh, (float*)d_out);
}

// Round 3
// 1248.345 us; speedup vs baseline: 1.8486x; 1.8486x over previous
//
#include <hip/hip_runtime.h>

// ---------------------------------------------------------------------------
// Local attention block, B=16 C=512 N=2048 — round 3 (= round-2 source, resubmitted
// after GPU-acquisition timeout; split-bf16 MFMA attention, unvalidated).
//   K1 k_proj   : fp32 GEMM -> writes xkT hi/lo (bf16, [n][d] transposed) and
//                 xv hi/lo (bf16, [c][n])
//   K2 k_stats  : MFMA energy pass 1 (row max / sumexp), split-3 bf16
//   K3 k_attn_pv: MFMA energy recompute (identical split/order) + P(bf16,hi) in
//                 LDS transposed + PV MFMA (vh,vl x p). u = x - xv@P
//   K4 k_trans  : fp32 GEMM t = wt@u + bt (+ BN atomics)
//   K5 k_bnfin, K6 k_out
// ws (bytes): xkT_hi 8.39M | xkT_lo 8.39M | xv_hi 33.55M | xv_lo 33.55M |
//             u 67.1M | rmax 131K | rinv 131K | bns/bnq/sc/sh 8K  = 151,265,280
// t (f32, 67.1M) overlays xv_hi+xv_lo (consumed before k_trans runs).
// ---------------------------------------------------------------------------

#define BB 16
#define CC 512
#define C4 128
#define NN 2048

typedef unsigned short u16;
typedef __attribute__((ext_vector_type(4))) unsigned short u16x4;
typedef __attribute__((ext_vector_type(8))) unsigned short u16x8;
typedef __attribute__((ext_vector_type(8))) short s16x8;
typedef __attribute__((ext_vector_type(4))) float f32x4;

#define MFMA(a, b, c) __builtin_amdgcn_mfma_f32_16x16x32_bf16((a), (b), (c), 0, 0, 0)

static __device__ __forceinline__ u16 f2bf(float f) {  // round-to-nearest-even
    unsigned u = __float_as_uint(f);
    return (u16)((u + 0x7fffu + ((u >> 16) & 1u)) >> 16);
}
static __device__ __forceinline__ float bf2f(u16 h) {
    return __uint_as_float((unsigned)h << 16);
}

// byte offsets into ws
static const size_t XKH_B  = 0;
static const size_t XKL_B  = 8388608;
static const size_t XVH_B  = 16777216;
static const size_t XVL_B  = 50331648;
static const size_t T_B    = 16777216;     // overlay on xv_hi+xv_lo
static const size_t U_B    = 83886080;
static const size_t RMAX_B = 150994944;
static const size_t RINV_B = 151126016;
static const size_t BNS_B  = 151257088;
static const size_t BNQ_B  = BNS_B + 2048;
static const size_t SC_B   = BNQ_B + 2048;
static const size_t SH_B   = SC_B + 2048;

// ---------------------------------------------------------------------------
// K1: projection GEMM (fp32 core). M=640 rows: 0..127 -> xkT splits (transposed
// epilogue via LDS), 128..639 -> xv splits (+bias).
// ---------------------------------------------------------------------------
__global__ __launch_bounds__(256) void k_proj(
    const float* __restrict__ x, const float* __restrict__ wqk,
    const float* __restrict__ wv, const float* __restrict__ bv,
    u16* __restrict__ xkh, u16* __restrict__ xkl,
    u16* __restrict__ xvh, u16* __restrict__ xvl)
{
    __shared__ float sraw[64 * 68];              // As | Bs, reused as T
    float (*As)[20] = (float(*)[20])sraw;        // 64x20
    float (*Bs)[68] = (float(*)[68])(sraw + 64 * 20);  // 16x68
    const int b = blockIdx.z, by = blockIdx.y, bx = blockIdx.x;
    const int tid = threadIdx.x;
    const int ty = tid >> 4, tx = tid & 15;
    const int ar = tid >> 2, ak = (tid & 3) << 2;
    const int br = tid >> 4, bc = (tid & 15) << 2;
    const int rowg = by * 64 + ar;
    const float* aptr = (rowg < C4) ? (wqk + (size_t)rowg * CC)
                                    : (wv + (size_t)(rowg - C4) * CC);
    const float* xb = x + (size_t)b * CC * NN;
    float acc[4][4] = {};
    for (int k0 = 0; k0 < CC; k0 += 16) {
        const float4 av = *(const float4*)(aptr + k0 + ak);
        const float4 bg = *(const float4*)(xb + (size_t)(k0 + br) * NN + bx * 64 + bc);
        __syncthreads();
        *(float4*)&As[ar][ak] = av;
        *(float4*)&Bs[br][bc] = bg;
        __syncthreads();
#pragma unroll
        for (int k = 0; k < 16; ++k) {
            const float4 bq = *(const float4*)&Bs[k][tx << 2];
            const float a0 = As[ty * 4 + 0][k];
            const float a1 = As[ty * 4 + 1][k];
            const float a2 = As[ty * 4 + 2][k];
            const float a3 = As[ty * 4 + 3][k];
            acc[0][0] += a0 * bq.x; acc[0][1] += a0 * bq.y; acc[0][2] += a0 * bq.z; acc[0][3] += a0 * bq.w;
            acc[1][0] += a1 * bq.x; acc[1][1] += a1 * bq.y; acc[1][2] += a1 * bq.z; acc[1][3] += a1 * bq.w;
            acc[2][0] += a2 * bq.x; acc[2][1] += a2 * bq.y; acc[2][2] += a2 * bq.z; acc[2][3] += a2 * bq.w;
            acc[3][0] += a3 * bq.x; acc[3][1] += a3 * bq.y; acc[3][2] += a3 * bq.z; acc[3][3] += a3 * bq.w;
        }
    }
    if (by < 2) {
        // xk rows (d = by*64 + ty*4+i). Transpose via LDS, emit xkT[n][d] hi/lo.
        __syncthreads();
        float (*T)[68] = (float(*)[68])sraw;
#pragma unroll
        for (int i = 0; i < 4; ++i) {
            float4 o; o.x = acc[i][0]; o.y = acc[i][1]; o.z = acc[i][2]; o.w = acc[i][3];
            *(float4*)&T[ty * 4 + i][tx * 4] = o;
        }
        __syncthreads();
        const int nl = tid >> 2, d0 = (tid & 3) * 16;
        u16x8 h0, h1, l0, l1;
#pragma unroll
        for (int j = 0; j < 8; ++j) {
            float v = T[d0 + j][nl];
            u16 h = f2bf(v); h0[j] = h; l0[j] = f2bf(v - bf2f(h));
        }
#pragma unroll
        for (int j = 0; j < 8; ++j) {
            float v = T[d0 + 8 + j][nl];
            u16 h = f2bf(v); h1[j] = h; l1[j] = f2bf(v - bf2f(h));
        }
        const size_t base = ((size_t)b * NN + bx * 64 + nl) * C4 + by * 64 + d0;
        *(u16x8*)(xkh + base) = h0; *(u16x8*)(xkh + base + 8) = h1;
        *(u16x8*)(xkl + base) = l0; *(u16x8*)(xkl + base + 8) = l1;
    } else {
        const int n = bx * 64 + (tx << 2);
#pragma unroll
        for (int i = 0; i < 4; ++i) {
            const int c = by * 64 - C4 + ty * 4 + i;
            const float bias = bv[c];
            u16x4 hq, lq;
#pragma unroll
            for (int j = 0; j < 4; ++j) {
                float v = acc[i][j] + bias;
                u16 h = f2bf(v); hq[j] = h; lq[j] = f2bf(v - bf2f(h));
            }
            const size_t off = ((size_t)b * CC + c) * NN + n;
            *(u16x4*)(xvh + off) = hq;
            *(u16x4*)(xvl + off) = lq;
        }
    }
}

// ---------------------------------------------------------------------------
// K2: energy pass 1 (MFMA, split-3). Block: 64 n-rows x all m. 4 waves, wave w
// owns n-rows w*16..+16. Online (max,sumexp) per lane, shfl-reduce over 16.
// ---------------------------------------------------------------------------
__global__ __launch_bounds__(256) void k_stats(
    const u16* __restrict__ xkh, const u16* __restrict__ xkl,
    float* __restrict__ rmax, float* __restrict__ rinv)
{
    const int b = blockIdx.y, nb = blockIdx.x;
    const int tid = threadIdx.x;
    const int w = tid >> 6, l = tid & 63;
    const int l15 = l & 15, lg = l >> 4;
    const u16* Hb = xkh + (size_t)b * NN * C4;
    const u16* Lb = xkl + (size_t)b * NN * C4;
    const size_t arow = (size_t)(nb * 64 + w * 16 + l15) * C4;
    // hoist A fragments (rows fixed for the whole kernel)
    s16x8 ah[4], al[4];
#pragma unroll
    for (int kk = 0; kk < 4; ++kk) {
        const int d = kk * 32 + lg * 8;
        ah[kk] = *reinterpret_cast<const s16x8*>(Hb + arow + d);
        al[kk] = *reinterpret_cast<const s16x8*>(Lb + arow + d);
    }
    float m[4], s[4];
#pragma unroll
    for (int r = 0; r < 4; ++r) { m[r] = -3.0e38f; s[r] = 0.0f; }

    for (int mt = 0; mt < NN / 64; ++mt) {
        f32x4 e[4];
#pragma unroll
        for (int ms = 0; ms < 4; ++ms) e[ms] = (f32x4){0.f, 0.f, 0.f, 0.f};
#pragma unroll
        for (int kk = 0; kk < 4; ++kk) {
            const int d = kk * 32 + lg * 8;
#pragma unroll
            for (int ms = 0; ms < 4; ++ms) {
                const size_t brow = (size_t)(mt * 64 + ms * 16 + l15) * C4;
                const s16x8 bh = *reinterpret_cast<const s16x8*>(Hb + brow + d);
                const s16x8 bl = *reinterpret_cast<const s16x8*>(Lb + brow + d);
                e[ms] = MFMA(ah[kk], bh, e[ms]);
                e[ms] = MFMA(al[kk], bh, e[ms]);
                e[ms] = MFMA(ah[kk], bl, e[ms]);
            }
        }
#pragma unroll
        for (int r = 0; r < 4; ++r) {
            const float v0 = e[0][r], v1 = e[1][r], v2 = e[2][r], v3 = e[3][r];
            const float vm = fmaxf(fmaxf(v0, v1), fmaxf(v2, v3));
            const float nm = fmaxf(m[r], vm);
            s[r] = s[r] * __expf(m[r] - nm) +
                   __expf(v0 - nm) + __expf(v1 - nm) + __expf(v2 - nm) + __expf(v3 - nm);
            m[r] = nm;
        }
    }
    // reduce across the 16 lanes (l15) sharing the same rows
#pragma unroll
    for (int off = 1; off < 16; off <<= 1) {
#pragma unroll
        for (int r = 0; r < 4; ++r) {
            const float mo = __shfl_xor(m[r], off);
            const float so = __shfl_xor(s[r], off);
            const float nm = fmaxf(m[r], mo);
            s[r] = s[r] * __expf(m[r] - nm) + so * __expf(mo - nm);
            m[r] = nm;
        }
    }
    if (l15 == 0) {
        const size_t base = (size_t)b * NN + nb * 64 + w * 16 + lg * 4;
#pragma unroll
        for (int r = 0; r < 4; ++r) {
            rmax[base + r] = m[r];
            rinv[base + r] = 1.0f / (s[r] * (1.0f + 1e-9f));
        }
    }
}

// ---------------------------------------------------------------------------
// K3: energy recompute (identical split/order) + P^T (bf16 hi) in LDS + PV.
// Block: m-block 64 x all 512 c, 8 waves. Wave w: E frags (nsub=w>>1,
// msubs=(w&1)*2+{0,1}); PV c-range w*64..+64.
// ---------------------------------------------------------------------------
__global__ __launch_bounds__(512, 2) void k_attn_pv(
    const u16* __restrict__ xkh, const u16* __restrict__ xkl,
    const u16* __restrict__ xvh, const u16* __restrict__ xvl,
    const float* __restrict__ x, const float* __restrict__ rmax,
    const float* __restrict__ rinv, float* __restrict__ u)
{
    __shared__ u16 pT[64][72];   // P^T tile: [m_local][n_local], pitch 144B
    const int b = blockIdx.y, mb = blockIdx.x;
    const int tid = threadIdx.x;
    const int w = tid >> 6, l = tid & 63;
    const int l15 = l & 15, lg = l >> 4;
    const int nsub = w >> 1, jb = (w & 1) * 2;
    const int M0 = mb * 64;
    const u16* Hb = xkh + (size_t)b * NN * C4;
    const u16* Lb = xkl + (size_t)b * NN * C4;
    const u16* Vh = xvh + (size_t)b * CC * NN;
    const u16* Vl = xvl + (size_t)b * CC * NN;

    // hoist E B-fragments (m-rows fixed per block)
    s16x8 bh[2][4], bl[2][4];
#pragma unroll
    for (int j = 0; j < 2; ++j) {
        const size_t mrow = (size_t)(M0 + (jb + j) * 16 + l15) * C4;
#pragma unroll
        for (int kk = 0; kk < 4; ++kk) {
            const int d = kk * 32 + lg * 8;
            bh[j][kk] = *reinterpret_cast<const s16x8*>(Hb + mrow + d);
            bl[j][kk] = *reinterpret_cast<const s16x8*>(Lb + mrow + d);
        }
    }
    f32x4 acc[4][4];
#pragma unroll
    for (int cs = 0; cs < 4; ++cs)
#pragma unroll
        for (int ms = 0; ms < 4; ++ms) acc[cs][ms] = (f32x4){0.f, 0.f, 0.f, 0.f};

    for (int nt = 0; nt < NN / 64; ++nt) {
        const int n0 = nt * 64;
        // ---- E (same split & order as k_stats) ----
        f32x4 e0 = {0.f, 0.f, 0.f, 0.f}, e1 = {0.f, 0.f, 0.f, 0.f};
        const size_t nrow = (size_t)(n0 + nsub * 16 + l15) * C4;
#pragma unroll
        for (int kk = 0; kk < 4; ++kk) {
            const int d = kk * 32 + lg * 8;
            const s16x8 ah = *reinterpret_cast<const s16x8*>(Hb + nrow + d);
            const s16x8 al = *reinterpret_cast<const s16x8*>(Lb + nrow + d);
            e0 = MFMA(ah, bh[0][kk], e0); e0 = MFMA(al, bh[0][kk], e0); e0 = MFMA(ah, bl[0][kk], e0);
            e1 = MFMA(ah, bh[1][kk], e1); e1 = MFMA(al, bh[1][kk], e1); e1 = MFMA(ah, bl[1][kk], e1);
        }
        // ---- softmax -> bf16 P ----
        const size_t rbase = (size_t)b * NN + n0 + nsub * 16 + lg * 4;
        const float4 rm = *(const float4*)(rmax + rbase);
        const float4 ri = *(const float4*)(rinv + rbase);
        u16x4 p0, p1;
        p0[0] = f2bf(__expf(e0[0] - rm.x) * ri.x);
        p0[1] = f2bf(__expf(e0[1] - rm.y) * ri.y);
        p0[2] = f2bf(__expf(e0[2] - rm.z) * ri.z);
        p0[3] = f2bf(__expf(e0[3] - rm.w) * ri.w);
        p1[0] = f2bf(__expf(e1[0] - rm.x) * ri.x);
        p1[1] = f2bf(__expf(e1[1] - rm.y) * ri.y);
        p1[2] = f2bf(__expf(e1[2] - rm.z) * ri.z);
        p1[3] = f2bf(__expf(e1[3] - rm.w) * ri.w);
        __syncthreads();   // previous PV reads of pT complete
        const int ncol = nsub * 16 + lg * 4;
        *reinterpret_cast<u16x4*>(&pT[(jb + 0) * 16 + l15][ncol]) = p0;
        *reinterpret_cast<u16x4*>(&pT[(jb + 1) * 16 + l15][ncol]) = p1;
        __syncthreads();   // pT ready
        // ---- PV: acc += xv(hi,lo) @ P ----
#pragma unroll
        for (int kk = 0; kk < 2; ++kk) {
            const int nn = kk * 32 + lg * 8;
            s16x8 avh[4], avl[4];
#pragma unroll
            for (int cs = 0; cs < 4; ++cs) {
                const size_t crow = (size_t)(w * 64 + cs * 16 + l15) * NN + n0 + nn;
                avh[cs] = *reinterpret_cast<const s16x8*>(Vh + crow);
                avl[cs] = *reinterpret_cast<const s16x8*>(Vl + crow);
            }
#pragma unroll
            for (int ms = 0; ms < 4; ++ms) {
                const s16x8 bp = *reinterpret_cast<const s16x8*>(&pT[ms * 16 + l15][nn]);
#pragma unroll
                for (int cs = 0; cs < 4; ++cs) {
                    acc[cs][ms] = MFMA(avh[cs], bp, acc[cs][ms]);
                    acc[cs][ms] = MFMA(avl[cs], bp, acc[cs][ms]);
                }
            }
        }
    }
    // ---- u = x - x_r ----
    const float* xb = x + (size_t)b * CC * NN;
    float* ub = u + (size_t)b * CC * NN;
#pragma unroll
    for (int cs = 0; cs < 4; ++cs) {
#pragma unroll
        for (int r = 0; r < 4; ++r) {
            const int c = w * 64 + cs * 16 + lg * 4 + r;
#pragma unroll
            for (int ms = 0; ms < 4; ++ms) {
                const size_t o = (size_t)c * NN + M0 + ms * 16 + l15;
                ub[o] = xb[o] - acc[cs][ms][r];
            }
        }
    }
}

// ---------------------------------------------------------------------------
// K4: t = wt @ u + bt, plus BN partial sums (unchanged fp32)
// ---------------------------------------------------------------------------
__global__ __launch_bounds__(256) void k_trans(
    const float* __restrict__ wt, const float* __restrict__ bt,
    const float* __restrict__ u, float* __restrict__ t,
    float* __restrict__ bns, float* __restrict__ bnq)
{
    __shared__ float As[64][20];
    __shared__ float Bs[16][68];
    const int b = blockIdx.z, by = blockIdx.y, bx = blockIdx.x;
    const int tid = threadIdx.x;
    const int ty = tid >> 4, tx = tid & 15;
    const int ar = tid >> 2, ak = (tid & 3) << 2;
    const int br = tid >> 4, bc = (tid & 15) << 2;
    const float* aptr = wt + (size_t)(by * 64 + ar) * CC;
    const float* ub = u + (size_t)b * CC * NN;
    float acc[4][4] = {};
    for (int k0 = 0; k0 < CC; k0 += 16) {
        const float4 av = *(const float4*)(aptr + k0 + ak);
        const float4 bg = *(const float4*)(ub + (size_t)(k0 + br) * NN + bx * 64 + bc);
        __syncthreads();
        *(float4*)&As[ar][ak] = av;
        *(float4*)&Bs[br][bc] = bg;
        __syncthreads();
#pragma unroll
        for (int k = 0; k < 16; ++k) {
            const float4 bq = *(const float4*)&Bs[k][tx << 2];
            const float a0 = As[ty * 4 + 0][k];
            const float a1 = As[ty * 4 + 1][k];
            const float a2 = As[ty * 4 + 2][k];
            const float a3 = As[ty * 4 + 3][k];
            acc[0][0] += a0 * bq.x; acc[0][1] += a0 * bq.y; acc[0][2] += a0 * bq.z; acc[0][3] += a0 * bq.w;
            acc[1][0] += a1 * bq.x; acc[1][1] += a1 * bq.y; acc[1][2] += a1 * bq.z; acc[1][3] += a1 * bq.w;
            acc[2][0] += a2 * bq.x; acc[2][1] += a2 * bq.y; acc[2][2] += a2 * bq.z; acc[2][3] += a2 * bq.w;
            acc[3][0] += a3 * bq.x; acc[3][1] += a3 * bq.y; acc[3][2] += a3 * bq.z; acc[3][3] += a3 * bq.w;
        }
    }
    float* tb = t + (size_t)b * CC * NN;
    const int n = bx * 64 + (tx << 2);
#pragma unroll
    for (int i = 0; i < 4; ++i) {
        const int r = by * 64 + ty * 4 + i;
        const float bias = bt[r];
        float4 o;
        o.x = acc[i][0] + bias; o.y = acc[i][1] + bias;
        o.z = acc[i][2] + bias; o.w = acc[i][3] + bias;
        *(float4*)(tb + (size_t)r * NN + n) = o;
        float rs = o.x + o.y + o.z + o.w;
        float rq = o.x * o.x + o.y * o.y + o.z * o.z + o.w * o.w;
#pragma unroll
        for (int off = 1; off < 16; off <<= 1) {
            rs += __shfl_xor(rs, off);
            rq += __shfl_xor(rq, off);
        }
        if (tx == 0) {
            atomicAdd(&bns[r], rs);
            atomicAdd(&bnq[r], rq);
        }
    }
}

__global__ void k_bnfin(const float* __restrict__ bns, const float* __restrict__ bnq,
                        const float* __restrict__ gamma, const float* __restrict__ beta,
                        float* __restrict__ scale, float* __restrict__ shift)
{
    const int c = threadIdx.x;
    if (c < CC) {
        const float inv = 1.0f / (float)(BB * NN);
        const float mean = bns[c] * inv;
        const float var = bnq[c] * inv - mean * mean;
        const float sc = gamma[c] * rsqrtf(var + 1e-5f);
        scale[c] = sc;
        shift[c] = beta[c] - mean * sc;
    }
}

__global__ __launch_bounds__(256) void k_out(
    const float* __restrict__ x, const float* __restrict__ t,
    const float* __restrict__ scale, const float* __restrict__ shift,
    float* __restrict__ out)
{
    const size_t total4 = (size_t)BB * CC * NN / 4;
    for (size_t idx = (size_t)blockIdx.x * blockDim.x + threadIdx.x; idx < total4;
         idx += (size_t)gridDim.x * blockDim.x) {
        const size_t e = idx * 4;
        const int c = (int)((e / NN) % CC);
        const float sc = scale[c], sh = shift[c];
        const float4 xq = ((const float4*)x)[idx];
        const float4 tq = ((const float4*)t)[idx];
        float4 o;
        o.x = xq.x + fmaxf(tq.x * sc + sh, 0.0f);
        o.y = xq.y + fmaxf(tq.y * sc + sh, 0.0f);
        o.z = xq.z + fmaxf(tq.z * sc + sh, 0.0f);
        o.w = xq.w + fmaxf(tq.w * sc + sh, 0.0f);
        ((float4*)out)[idx] = o;
    }
}

// ---------------------------------------------------------------------------
extern "C" void kernel_launch(void* const* d_in, const int* in_sizes, int n_in,
                              void* d_out, int out_size, void* d_ws, size_t ws_size,
                              hipStream_t stream)
{
    const float* x     = (const float*)d_in[0];
    const float* wqk   = (const float*)d_in[1];
    const float* wv    = (const float*)d_in[2];
    const float* bv    = (const float*)d_in[3];
    const float* wt    = (const float*)d_in[4];
    const float* bt    = (const float*)d_in[5];
    const float* gamma = (const float*)d_in[6];
    const float* beta  = (const float*)d_in[7];
    char* ws = (char*)d_ws;

    u16*   xkh  = (u16*)(ws + XKH_B);
    u16*   xkl  = (u16*)(ws + XKL_B);
    u16*   xvh  = (u16*)(ws + XVH_B);
    u16*   xvl  = (u16*)(ws + XVL_B);
    float* t    = (float*)(ws + T_B);      // overlay on xv_hi+xv_lo
    float* ub   = (float*)(ws + U_B);
    float* rmax = (float*)(ws + RMAX_B);
    float* rinv = (float*)(ws + RINV_B);
    float* bns  = (float*)(ws + BNS_B);
    float* bnq  = (float*)(ws + BNQ_B);
    float* sc   = (float*)(ws + SC_B);
    float* sh   = (float*)(ws + SH_B);

    hipMemsetAsync(bns, 0, 2 * CC * sizeof(float), stream);  // bns+bnq contiguous

    k_proj<<<dim3(NN / 64, 10, BB), 256, 0, stream>>>(x, wqk, wv, bv, xkh, xkl, xvh, xvl);
    k_stats<<<dim3(NN / 64, BB), 256, 0, stream>>>(xkh, xkl, rmax, rinv);
    k_attn_pv<<<dim3(NN / 64, BB), 512, 0, stream>>>(xkh, xkl, xvh, xvl, x, rmax, rinv, ub);
    k_trans<<<dim3(NN / 64, 8, BB), 256, 0, stream>>>(wt, bt, ub, t, bns, bnq);
    k_bnfin<<<1, 512, 0, stream>>>(bns, bnq, gamma, beta, sc, sh);
    k_out<<<2048, 256, 0, stream>>>(x, t, sc, sh, (float*)d_out);
}

// Round 5
// 1154.408 us; speedup vs baseline: 1.9991x; 1.0814x over previous
//
#include <hip/hip_runtime.h>

// ---------------------------------------------------------------------------
// Local attention block, B=16 C=512 N=2048 — round 5 (= round-4 source,
// resubmitted after GPU-acquisition timeout; all four GEMMs on MFMA).
//   K0 k_wsplit   : W=[wqk;wv;wt] (1152x512 f32) -> bf16 hi/lo
//   K1 k_split_t  : x [c][n] f32 -> xT [n][c] bf16 hi/lo   (also reused for u)
//   K2 k_proj_mfma: xk = wqk@x (transposed epilogue -> xkT hi/lo),
//                   xv = wv@x + bv (hi/lo)        [split-3 bf16 MFMA]
//   K3 k_stats    : energy pass 1 (unchanged, validated)
//   K4 k_attn_pv  : energy recompute + P + PV (unchanged, validated)
//   K5 k_split_t  : u -> uT hi/lo
//   K6 k_trans_mfma: t = wt@u + bt (f32 out) + BN partial sums
//   K7 k_bnfin, K8 k_out
// ws overlays (peak ~153.6 MB):
//   [0, 16.8M)      xkT hi/lo
//   [16.8M, 83.9M)  xv hi/lo  -> later uT hi/lo
//   [83.9M, 151M)   xT hi/lo  -> later u f32 -> later t f32
//   [151M, 153.4M)  W hi/lo
//   [153.4M, ...)   rmax/rinv/bns/bnq/sc/sh
// ---------------------------------------------------------------------------

#define BB 16
#define CC 512
#define C4 128
#define NN 2048

typedef unsigned short u16;
typedef __attribute__((ext_vector_type(4))) unsigned short u16x4;
typedef __attribute__((ext_vector_type(8))) unsigned short u16x8;
typedef __attribute__((ext_vector_type(8))) short s16x8;
typedef __attribute__((ext_vector_type(4))) float f32x4;

#define MFMA(a, b, c) __builtin_amdgcn_mfma_f32_16x16x32_bf16((a), (b), (c), 0, 0, 0)

static __device__ __forceinline__ u16 f2bf(float f) {  // round-to-nearest-even
    unsigned u = __float_as_uint(f);
    return (u16)((u + 0x7fffu + ((u >> 16) & 1u)) >> 16);
}
static __device__ __forceinline__ float bf2f(u16 h) {
    return __uint_as_float((unsigned)h << 16);
}

// byte offsets into ws
static const size_t XKH_B  = 0;                         //  8,388,608
static const size_t XKL_B  = 8388608;                   //  8,388,608
static const size_t XVH_B  = 16777216;                  // 33,554,432 (-> uT hi)
static const size_t XVL_B  = 50331648;                  // 33,554,432 (-> uT lo)
static const size_t XT_B   = 83886080;                  // 67,108,864 (xT hi+lo -> u f32 -> t f32)
static const size_t W_B    = 150994944;                 //  2,359,296 (hi+lo)
static const size_t RMAX_B = 153354240;
static const size_t RINV_B = RMAX_B + 131072;
static const size_t BNS_B  = RINV_B + 131072;
static const size_t BNQ_B  = BNS_B + 2048;
static const size_t SC_B   = BNQ_B + 2048;
static const size_t SH_B   = SC_B + 2048;

// ---------------------------------------------------------------------------
// K0: split W = [wqk(128) ; wv(512) ; wt(512)] rows x 512 into bf16 hi/lo.
// ---------------------------------------------------------------------------
__global__ __launch_bounds__(256) void k_wsplit(
    const float* __restrict__ wqk, const float* __restrict__ wv,
    const float* __restrict__ wt, u16* __restrict__ wh, u16* __restrict__ wl)
{
    const int idx = blockIdx.x * 256 + threadIdx.x;      // grid 576 -> exact
    const int e = idx * 4;
    const int row = e >> 9, col = e & 511;
    const float* src = (row < 128) ? (wqk + (size_t)row * 512 + col)
                     : (row < 640) ? (wv + (size_t)(row - 128) * 512 + col)
                                   : (wt + (size_t)(row - 640) * 512 + col);
    const float4 v = *(const float4*)src;
    u16x4 h, lo;
    h[0] = f2bf(v.x); lo[0] = f2bf(v.x - bf2f(h[0]));
    h[1] = f2bf(v.y); lo[1] = f2bf(v.y - bf2f(h[1]));
    h[2] = f2bf(v.z); lo[2] = f2bf(v.z - bf2f(h[2]));
    h[3] = f2bf(v.w); lo[3] = f2bf(v.w - bf2f(h[3]));
    *(u16x4*)(wh + e) = h;
    *(u16x4*)(wl + e) = lo;
}

// ---------------------------------------------------------------------------
// K1: transpose + split. src [b][512][2048] f32 -> dst hi/lo [b][2048][512] u16.
// Tile 64r x 64n, 256 threads, LDS pitch 69 (bank-safe scalar access).
// ---------------------------------------------------------------------------
__global__ __launch_bounds__(256) void k_split_t(
    const float* __restrict__ src, u16* __restrict__ dh, u16* __restrict__ dl)
{
    __shared__ float S[64][69];
    const int b = blockIdx.z, rt = blockIdx.y, nt = blockIdx.x;
    const int tid = threadIdx.x;
    {   // load 64x64 f32 tile, coalesced (per q: 64B-contig per row quarter)
        const int rl = tid >> 2, c4 = (tid & 3) * 4;
        const float* sp = src + ((size_t)b * CC + rt * 64 + rl) * NN + nt * 64;
#pragma unroll
        for (int q = 0; q < 4; ++q) {
            const float4 v = *(const float4*)(sp + c4 + q * 16);
            const int col = c4 + q * 16;
            S[rl][col] = v.x; S[rl][col + 1] = v.y; S[rl][col + 2] = v.z; S[rl][col + 3] = v.w;
        }
    }
    __syncthreads();
    const int c0 = (tid & 7) * 8;
#pragma unroll
    for (int p = 0; p < 2; ++p) {
        const int n_local = p * 32 + (tid >> 3);
        u16x8 h, lo;
#pragma unroll
        for (int j = 0; j < 8; ++j) {
            const float v = S[c0 + j][n_local];
            const u16 hh = f2bf(v);
            h[j] = hh; lo[j] = f2bf(v - bf2f(hh));
        }
        const size_t off = ((size_t)b * NN + nt * 64 + n_local) * CC + rt * 64 + c0;
        *(u16x8*)(dh + off) = h;
        *(u16x8*)(dl + off) = lo;
    }
}

// ---------------------------------------------------------------------------
// K2: projection GEMM, split-3 bf16 MFMA. Block 128m x 128n, 4 waves (2x2),
// each wave 64x64 (acc f32x4[4][4]). mb==0 -> xk rows (transpose epilogue);
// mb>=1 -> xv rows c=m-128 (+bias, hi/lo split stores).
// Layout convention (validated in k_stats/k_attn_pv): D row = lg*4+r (A-side),
// D col = l15 (B-side); A-frag row selected by l15 at load.
// ---------------------------------------------------------------------------
__global__ __launch_bounds__(256, 3) void k_proj_mfma(
    const u16* __restrict__ wh, const u16* __restrict__ wl,
    const u16* __restrict__ xth, const u16* __restrict__ xtl,
    const float* __restrict__ bv,
    u16* __restrict__ xkh, u16* __restrict__ xkl,
    u16* __restrict__ xvh, u16* __restrict__ xvl)
{
    __shared__ u16 Tt[128][136];
    const int b = blockIdx.z, mb = blockIdx.y, nb = blockIdx.x;
    const int tid = threadIdx.x;
    const int w = tid >> 6, l = tid & 63;
    const int l15 = l & 15, lg = l >> 4;
    const int wm = w >> 1, wn = w & 1;
    const int m0 = mb * 128 + wm * 64;       // W row base
    const int n0 = nb * 128 + wn * 64;       // col base within batch
    const u16* Bh = xth + (size_t)b * NN * CC;
    const u16* Bl = xtl + (size_t)b * NN * CC;

    f32x4 acc[4][4];
#pragma unroll
    for (int am = 0; am < 4; ++am)
#pragma unroll
        for (int an = 0; an < 4; ++an) acc[am][an] = (f32x4){0.f, 0.f, 0.f, 0.f};

    for (int kk = 0; kk < 16; ++kk) {
        const int d = kk * 32 + lg * 8;
        s16x8 ah[4], al[4], bh4[4], bl4[4];
#pragma unroll
        for (int am = 0; am < 4; ++am) {
            const size_t ro = (size_t)(m0 + am * 16 + l15) * CC + d;
            ah[am] = *reinterpret_cast<const s16x8*>(wh + ro);
            al[am] = *reinterpret_cast<const s16x8*>(wl + ro);
        }
#pragma unroll
        for (int an = 0; an < 4; ++an) {
            const size_t ro = (size_t)(n0 + an * 16 + l15) * CC + d;
            bh4[an] = *reinterpret_cast<const s16x8*>(Bh + ro);
            bl4[an] = *reinterpret_cast<const s16x8*>(Bl + ro);
        }
#pragma unroll
        for (int am = 0; am < 4; ++am)
#pragma unroll
            for (int an = 0; an < 4; ++an) {
                acc[am][an] = MFMA(ah[am], bh4[an], acc[am][an]);
                acc[am][an] = MFMA(al[am], bh4[an], acc[am][an]);
                acc[am][an] = MFMA(ah[am], bl4[an], acc[am][an]);
            }
    }

    if (mb == 0) {
        // xk rows: d = m0 + am*16 + lg*4 + r (0..127), n_local = wn*64+an*16+l15.
        // Emit xkT[n][d] hi then lo via LDS transpose.
#pragma unroll
        for (int pass = 0; pass < 2; ++pass) {
            if (pass) __syncthreads();
#pragma unroll
            for (int am = 0; am < 4; ++am)
#pragma unroll
                for (int an = 0; an < 4; ++an) {
                    const int nl = wn * 64 + an * 16 + l15;
                    const int dbase = wm * 64 + am * 16 + lg * 4;
#pragma unroll
                    for (int r = 0; r < 4; ++r) {
                        const float v = acc[am][an][r];
                        const u16 h = f2bf(v);
                        Tt[nl][dbase + r] = pass ? f2bf(v - bf2f(h)) : h;
                    }
                }
            __syncthreads();
            u16* dst = pass ? xkl : xkh;
            const int c8 = (tid & 15) * 8;
#pragma unroll
            for (int rd = 0; rd < 8; ++rd) {
                const int row = rd * 16 + (tid >> 4);
                *(u16x8*)(dst + ((size_t)b * NN + nb * 128 + row) * C4 + c8) =
                    *(const u16x8*)&Tt[row][c8];
            }
        }
    } else {
        // xv rows: c = m0 - 128 + am*16 + lg*4 + r
#pragma unroll
        for (int am = 0; am < 4; ++am) {
            const int cb = m0 - C4 + am * 16 + lg * 4;
#pragma unroll
            for (int r = 0; r < 4; ++r) {
                const int c = cb + r;
                const float bias = bv[c];
#pragma unroll
                for (int an = 0; an < 4; ++an) {
                    const float v = acc[am][an][r] + bias;
                    const u16 h = f2bf(v);
                    const size_t off = ((size_t)b * CC + c) * NN + n0 + an * 16 + l15;
                    xvh[off] = h;
                    xvl[off] = f2bf(v - bf2f(h));
                }
            }
        }
    }
}

// ---------------------------------------------------------------------------
// K3: energy pass 1 (unchanged, validated).
// ---------------------------------------------------------------------------
__global__ __launch_bounds__(256) void k_stats(
    const u16* __restrict__ xkh, const u16* __restrict__ xkl,
    float* __restrict__ rmax, float* __restrict__ rinv)
{
    const int b = blockIdx.y, nb = blockIdx.x;
    const int tid = threadIdx.x;
    const int w = tid >> 6, l = tid & 63;
    const int l15 = l & 15, lg = l >> 4;
    const u16* Hb = xkh + (size_t)b * NN * C4;
    const u16* Lb = xkl + (size_t)b * NN * C4;
    const size_t arow = (size_t)(nb * 64 + w * 16 + l15) * C4;
    s16x8 ah[4], al[4];
#pragma unroll
    for (int kk = 0; kk < 4; ++kk) {
        const int d = kk * 32 + lg * 8;
        ah[kk] = *reinterpret_cast<const s16x8*>(Hb + arow + d);
        al[kk] = *reinterpret_cast<const s16x8*>(Lb + arow + d);
    }
    float m[4], s[4];
#pragma unroll
    for (int r = 0; r < 4; ++r) { m[r] = -3.0e38f; s[r] = 0.0f; }

    for (int mt = 0; mt < NN / 64; ++mt) {
        f32x4 e[4];
#pragma unroll
        for (int ms = 0; ms < 4; ++ms) e[ms] = (f32x4){0.f, 0.f, 0.f, 0.f};
#pragma unroll
        for (int kk = 0; kk < 4; ++kk) {
            const int d = kk * 32 + lg * 8;
#pragma unroll
            for (int ms = 0; ms < 4; ++ms) {
                const size_t brow = (size_t)(mt * 64 + ms * 16 + l15) * C4;
                const s16x8 bh = *reinterpret_cast<const s16x8*>(Hb + brow + d);
                const s16x8 bl = *reinterpret_cast<const s16x8*>(Lb + brow + d);
                e[ms] = MFMA(ah[kk], bh, e[ms]);
                e[ms] = MFMA(al[kk], bh, e[ms]);
                e[ms] = MFMA(ah[kk], bl, e[ms]);
            }
        }
#pragma unroll
        for (int r = 0; r < 4; ++r) {
            const float v0 = e[0][r], v1 = e[1][r], v2 = e[2][r], v3 = e[3][r];
            const float vm = fmaxf(fmaxf(v0, v1), fmaxf(v2, v3));
            const float nm = fmaxf(m[r], vm);
            s[r] = s[r] * __expf(m[r] - nm) +
                   __expf(v0 - nm) + __expf(v1 - nm) + __expf(v2 - nm) + __expf(v3 - nm);
            m[r] = nm;
        }
    }
#pragma unroll
    for (int off = 1; off < 16; off <<= 1) {
#pragma unroll
        for (int r = 0; r < 4; ++r) {
            const float mo = __shfl_xor(m[r], off);
            const float so = __shfl_xor(s[r], off);
            const float nm = fmaxf(m[r], mo);
            s[r] = s[r] * __expf(m[r] - nm) + so * __expf(mo - nm);
            m[r] = nm;
        }
    }
    if (l15 == 0) {
        const size_t base = (size_t)b * NN + nb * 64 + w * 16 + lg * 4;
#pragma unroll
        for (int r = 0; r < 4; ++r) {
            rmax[base + r] = m[r];
            rinv[base + r] = 1.0f / (s[r] * (1.0f + 1e-9f));
        }
    }
}

// ---------------------------------------------------------------------------
// K4: energy recompute + P + PV (unchanged, validated).
// ---------------------------------------------------------------------------
__global__ __launch_bounds__(512, 2) void k_attn_pv(
    const u16* __restrict__ xkh, const u16* __restrict__ xkl,
    const u16* __restrict__ xvh, const u16* __restrict__ xvl,
    const float* __restrict__ x, const float* __restrict__ rmax,
    const float* __restrict__ rinv, float* __restrict__ u)
{
    __shared__ u16 pT[64][72];
    const int b = blockIdx.y, mb = blockIdx.x;
    const int tid = threadIdx.x;
    const int w = tid >> 6, l = tid & 63;
    const int l15 = l & 15, lg = l >> 4;
    const int nsub = w >> 1, jb = (w & 1) * 2;
    const int M0 = mb * 64;
    const u16* Hb = xkh + (size_t)b * NN * C4;
    const u16* Lb = xkl + (size_t)b * NN * C4;
    const u16* Vh = xvh + (size_t)b * CC * NN;
    const u16* Vl = xvl + (size_t)b * CC * NN;

    s16x8 bh[2][4], bl[2][4];
#pragma unroll
    for (int j = 0; j < 2; ++j) {
        const size_t mrow = (size_t)(M0 + (jb + j) * 16 + l15) * C4;
#pragma unroll
        for (int kk = 0; kk < 4; ++kk) {
            const int d = kk * 32 + lg * 8;
            bh[j][kk] = *reinterpret_cast<const s16x8*>(Hb + mrow + d);
            bl[j][kk] = *reinterpret_cast<const s16x8*>(Lb + mrow + d);
        }
    }
    f32x4 acc[4][4];
#pragma unroll
    for (int cs = 0; cs < 4; ++cs)
#pragma unroll
        for (int ms = 0; ms < 4; ++ms) acc[cs][ms] = (f32x4){0.f, 0.f, 0.f, 0.f};

    for (int nt = 0; nt < NN / 64; ++nt) {
        const int n0 = nt * 64;
        f32x4 e0 = {0.f, 0.f, 0.f, 0.f}, e1 = {0.f, 0.f, 0.f, 0.f};
        const size_t nrow = (size_t)(n0 + nsub * 16 + l15) * C4;
#pragma unroll
        for (int kk = 0; kk < 4; ++kk) {
            const int d = kk * 32 + lg * 8;
            const s16x8 ah = *reinterpret_cast<const s16x8*>(Hb + nrow + d);
            const s16x8 al = *reinterpret_cast<const s16x8*>(Lb + nrow + d);
            e0 = MFMA(ah, bh[0][kk], e0); e0 = MFMA(al, bh[0][kk], e0); e0 = MFMA(ah, bl[0][kk], e0);
            e1 = MFMA(ah, bh[1][kk], e1); e1 = MFMA(al, bh[1][kk], e1); e1 = MFMA(ah, bl[1][kk], e1);
        }
        const size_t rbase = (size_t)b * NN + n0 + nsub * 16 + lg * 4;
        const float4 rm = *(const float4*)(rmax + rbase);
        const float4 ri = *(const float4*)(rinv + rbase);
        u16x4 p0, p1;
        p0[0] = f2bf(__expf(e0[0] - rm.x) * ri.x);
        p0[1] = f2bf(__expf(e0[1] - rm.y) * ri.y);
        p0[2] = f2bf(__expf(e0[2] - rm.z) * ri.z);
        p0[3] = f2bf(__expf(e0[3] - rm.w) * ri.w);
        p1[0] = f2bf(__expf(e1[0] - rm.x) * ri.x);
        p1[1] = f2bf(__expf(e1[1] - rm.y) * ri.y);
        p1[2] = f2bf(__expf(e1[2] - rm.z) * ri.z);
        p1[3] = f2bf(__expf(e1[3] - rm.w) * ri.w);
        __syncthreads();
        const int ncol = nsub * 16 + lg * 4;
        *reinterpret_cast<u16x4*>(&pT[(jb + 0) * 16 + l15][ncol]) = p0;
        *reinterpret_cast<u16x4*>(&pT[(jb + 1) * 16 + l15][ncol]) = p1;
        __syncthreads();
#pragma unroll
        for (int kk = 0; kk < 2; ++kk) {
            const int nn = kk * 32 + lg * 8;
            s16x8 avh[4], avl[4];
#pragma unroll
            for (int cs = 0; cs < 4; ++cs) {
                const size_t crow = (size_t)(w * 64 + cs * 16 + l15) * NN + n0 + nn;
                avh[cs] = *reinterpret_cast<const s16x8*>(Vh + crow);
                avl[cs] = *reinterpret_cast<const s16x8*>(Vl + crow);
            }
#pragma unroll
            for (int ms = 0; ms < 4; ++ms) {
                const s16x8 bp = *reinterpret_cast<const s16x8*>(&pT[ms * 16 + l15][nn]);
#pragma unroll
                for (int cs = 0; cs < 4; ++cs) {
                    acc[cs][ms] = MFMA(avh[cs], bp, acc[cs][ms]);
                    acc[cs][ms] = MFMA(avl[cs], bp, acc[cs][ms]);
                }
            }
        }
    }
    const float* xb = x + (size_t)b * CC * NN;
    float* ub = u + (size_t)b * CC * NN;
#pragma unroll
    for (int cs = 0; cs < 4; ++cs) {
#pragma unroll
        for (int r = 0; r < 4; ++r) {
            const int c = w * 64 + cs * 16 + lg * 4 + r;
#pragma unroll
            for (int ms = 0; ms < 4; ++ms) {
                const size_t o = (size_t)c * NN + M0 + ms * 16 + l15;
                ub[o] = xb[o] - acc[cs][ms][r];
            }
        }
    }
}

// ---------------------------------------------------------------------------
// K6: t = wt@u + bt (split-3 bf16 MFMA) + BN partial sums. W rows 640..1151.
// ---------------------------------------------------------------------------
__global__ __launch_bounds__(256, 3) void k_trans_mfma(
    const u16* __restrict__ wh, const u16* __restrict__ wl,
    const u16* __restrict__ uth, const u16* __restrict__ utl,
    const float* __restrict__ bt, float* __restrict__ t,
    float* __restrict__ bns, float* __restrict__ bnq)
{
    const int b = blockIdx.z, mb = blockIdx.y, nb = blockIdx.x;
    const int tid = threadIdx.x;
    const int w = tid >> 6, l = tid & 63;
    const int l15 = l & 15, lg = l >> 4;
    const int wm = w >> 1, wn = w & 1;
    const int m0 = mb * 128 + wm * 64;       // c_out base (0..511)
    const int n0 = nb * 128 + wn * 64;
    const u16* Bh = uth + (size_t)b * NN * CC;
    const u16* Bl = utl + (size_t)b * NN * CC;

    f32x4 acc[4][4];
#pragma unroll
    for (int am = 0; am < 4; ++am)
#pragma unroll
        for (int an = 0; an < 4; ++an) acc[am][an] = (f32x4){0.f, 0.f, 0.f, 0.f};

    for (int kk = 0; kk < 16; ++kk) {
        const int d = kk * 32 + lg * 8;
        s16x8 ah[4], al[4], bh4[4], bl4[4];
#pragma unroll
        for (int am = 0; am < 4; ++am) {
            const size_t ro = (size_t)(640 + m0 + am * 16 + l15) * CC + d;
            ah[am] = *reinterpret_cast<const s16x8*>(wh + ro);
            al[am] = *reinterpret_cast<const s16x8*>(wl + ro);
        }
#pragma unroll
        for (int an = 0; an < 4; ++an) {
            const size_t ro = (size_t)(n0 + an * 16 + l15) * CC + d;
            bh4[an] = *reinterpret_cast<const s16x8*>(Bh + ro);
            bl4[an] = *reinterpret_cast<const s16x8*>(Bl + ro);
        }
#pragma unroll
        for (int am = 0; am < 4; ++am)
#pragma unroll
            for (int an = 0; an < 4; ++an) {
                acc[am][an] = MFMA(ah[am], bh4[an], acc[am][an]);
                acc[am][an] = MFMA(al[am], bh4[an], acc[am][an]);
                acc[am][an] = MFMA(ah[am], bl4[an], acc[am][an]);
            }
    }

    float* tb = t + (size_t)b * CC * NN;
#pragma unroll
    for (int am = 0; am < 4; ++am) {
        const int cb = m0 + am * 16 + lg * 4;
        float rs[4], rq[4];
#pragma unroll
        for (int r = 0; r < 4; ++r) { rs[r] = 0.f; rq[r] = 0.f; }
#pragma unroll
        for (int r = 0; r < 4; ++r) {
            const int c = cb + r;
            const float bias = bt[c];
#pragma unroll
            for (int an = 0; an < 4; ++an) {
                const float v = acc[am][an][r] + bias;
                tb[(size_t)c * NN + n0 + an * 16 + l15] = v;
                rs[r] += v;
                rq[r] += v * v;
            }
        }
#pragma unroll
        for (int off = 1; off < 16; off <<= 1) {
#pragma unroll
            for (int r = 0; r < 4; ++r) {
                rs[r] += __shfl_xor(rs[r], off);
                rq[r] += __shfl_xor(rq[r], off);
            }
        }
        if (l15 == 0) {
#pragma unroll
            for (int r = 0; r < 4; ++r) {
                atomicAdd(&bns[cb + r], rs[r]);
                atomicAdd(&bnq[cb + r], rq[r]);
            }
        }
    }
}

// ---------------------------------------------------------------------------
__global__ void k_bnfin(const float* __restrict__ bns, const float* __restrict__ bnq,
                        const float* __restrict__ gamma, const float* __restrict__ beta,
                        float* __restrict__ scale, float* __restrict__ shift)
{
    const int c = threadIdx.x;
    if (c < CC) {
        const float inv = 1.0f / (float)(BB * NN);
        const float mean = bns[c] * inv;
        const float var = bnq[c] * inv - mean * mean;
        const float sc = gamma[c] * rsqrtf(var + 1e-5f);
        scale[c] = sc;
        shift[c] = beta[c] - mean * sc;
    }
}

__global__ __launch_bounds__(256) void k_out(
    const float* __restrict__ x, const float* __restrict__ t,
    const float* __restrict__ scale, const float* __restrict__ shift,
    float* __restrict__ out)
{
    const size_t total4 = (size_t)BB * CC * NN / 4;
    for (size_t idx = (size_t)blockIdx.x * blockDim.x + threadIdx.x; idx < total4;
         idx += (size_t)gridDim.x * blockDim.x) {
        const size_t e = idx * 4;
        const int c = (int)((e / NN) % CC);
        const float sc = scale[c], sh = shift[c];
        const float4 xq = ((const float4*)x)[idx];
        const float4 tq = ((const float4*)t)[idx];
        float4 o;
        o.x = xq.x + fmaxf(tq.x * sc + sh, 0.0f);
        o.y = xq.y + fmaxf(tq.y * sc + sh, 0.0f);
        o.z = xq.z + fmaxf(tq.z * sc + sh, 0.0f);
        o.w = xq.w + fmaxf(tq.w * sc + sh, 0.0f);
        ((float4*)out)[idx] = o;
    }
}

// ---------------------------------------------------------------------------
extern "C" void kernel_launch(void* const* d_in, const int* in_sizes, int n_in,
                              void* d_out, int out_size, void* d_ws, size_t ws_size,
                              hipStream_t stream)
{
    const float* x     = (const float*)d_in[0];
    const float* wqk   = (const float*)d_in[1];
    const float* wv    = (const float*)d_in[2];
    const float* bv    = (const float*)d_in[3];
    const float* wt    = (const float*)d_in[4];
    const float* bt    = (const float*)d_in[5];
    const float* gamma = (const float*)d_in[6];
    const float* beta  = (const float*)d_in[7];
    char* ws = (char*)d_ws;

    u16*   xkh  = (u16*)(ws + XKH_B);
    u16*   xkl  = (u16*)(ws + XKL_B);
    u16*   xvh  = (u16*)(ws + XVH_B);
    u16*   xvl  = (u16*)(ws + XVL_B);
    u16*   uth  = (u16*)(ws + XVH_B);      // overlay (xv dead after k_attn_pv)
    u16*   utl  = (u16*)(ws + XVL_B);
    u16*   xth  = (u16*)(ws + XT_B);
    u16*   xtl  = (u16*)(ws + XT_B + 33554432);
    float* ub   = (float*)(ws + XT_B);     // overlay (xT dead after k_proj_mfma)
    float* t    = (float*)(ws + XT_B);     // overlay (u dead after 2nd k_split_t)
    u16*   wh   = (u16*)(ws + W_B);
    u16*   wl   = (u16*)(ws + W_B + 1179648);
    float* rmax = (float*)(ws + RMAX_B);
    float* rinv = (float*)(ws + RINV_B);
    float* bns  = (float*)(ws + BNS_B);
    float* bnq  = (float*)(ws + BNQ_B);
    float* sc   = (float*)(ws + SC_B);
    float* sh   = (float*)(ws + SH_B);

    hipMemsetAsync(bns, 0, 2 * CC * sizeof(float), stream);  // bns+bnq contiguous

    k_wsplit<<<576, 256, 0, stream>>>(wqk, wv, wt, wh, wl);
    k_split_t<<<dim3(32, 8, BB), 256, 0, stream>>>(x, xth, xtl);
    k_proj_mfma<<<dim3(16, 5, BB), 256, 0, stream>>>(wh, wl, xth, xtl, bv,
                                                     xkh, xkl, xvh, xvl);
    k_stats<<<dim3(32, BB), 256, 0, stream>>>(xkh, xkl, rmax, rinv);
    k_attn_pv<<<dim3(32, BB), 512, 0, stream>>>(xkh, xkl, xvh, xvl, x, rmax, rinv, ub);
    k_split_t<<<dim3(32, 8, BB), 256, 0, stream>>>(ub, uth, utl);
    k_trans_mfma<<<dim3(16, 4, BB), 256, 0, stream>>>(wh, wl, uth, utl, bt, t, bns, bnq);
    k_bnfin<<<1, 512, 0, stream>>>(bns, bnq, gamma, beta, sc, sh);
    k_out<<<2048, 256, 0, stream>>>(x, t, sc, sh, (float*)d_out);
}

// Round 7
// 729.602 us; speedup vs baseline: 3.1630x; 1.5822x over previous
//
#include <hip/hip_runtime.h>

// ---------------------------------------------------------------------------
// Round 7 (= round-6 source, resubmitted after GPU-acquisition timeout).
// Fragment-ordered operands. Every MFMA operand buffer is stored in fragment
// order: one 16(row) x 32(K) bf16 fragment = 1KB contiguous, with elem
// (row_local, d_local) at ((d_local>>3)*16 + row_local)*8 + (d_local&7),
// so lane l reads its 16B at frag_base + l*16 -> one coalesced 1KB load per
// wave instead of 64 scattered 16B requests (the round-5 latency bottleneck:
// MfmaUtil 18%, VALUBusy 9%, HBM 13% on every GEMM-shaped kernel).
//   frag spaces (per batch where applicable):
//     wF  [72 g16][16 kk]           (W = [wqk;wv;wt])
//     xtF/utF [b][128 g16][16 kk]   (xT/uT: rows = n, K = c)
//     xkF [b][128 g16][4 kk]        (rows = n, K = d)
//     xvF [b][64 nk][32 cg]         (rows = c, K = n-chunk 32)
// Arithmetic bit-identical to round 5 (layout-only change).
// ---------------------------------------------------------------------------

#define BB 16
#define CC 512
#define C4 128
#define NN 2048

typedef unsigned short u16;
typedef __attribute__((ext_vector_type(4))) unsigned short u16x4;
typedef __attribute__((ext_vector_type(8))) unsigned short u16x8;
typedef __attribute__((ext_vector_type(8))) short s16x8;
typedef __attribute__((ext_vector_type(4))) float f32x4;

#define MFMA(a, b, c) __builtin_amdgcn_mfma_f32_16x16x32_bf16((a), (b), (c), 0, 0, 0)

static __device__ __forceinline__ u16 f2bf(float f) {  // round-to-nearest-even
    unsigned u = __float_as_uint(f);
    return (u16)((u + 0x7fffu + ((u >> 16) & 1u)) >> 16);
}
static __device__ __forceinline__ float bf2f(u16 h) {
    return __uint_as_float((unsigned)h << 16);
}
static __device__ __forceinline__ s16x8 ldfrag(const u16* __restrict__ p, size_t fi, int l) {
    return *reinterpret_cast<const s16x8*>(p + fi * 512 + l * 8);
}

// byte offsets into ws (sizes/overlays identical to round 5)
static const size_t XKH_B  = 0;
static const size_t XKL_B  = 8388608;
static const size_t XVH_B  = 16777216;
static const size_t XVL_B  = 50331648;
static const size_t XT_B   = 83886080;
static const size_t W_B    = 150994944;
static const size_t RMAX_B = 153354240;
static const size_t RINV_B = RMAX_B + 131072;
static const size_t BNS_B  = RINV_B + 131072;
static const size_t BNQ_B  = BNS_B + 2048;
static const size_t SC_B   = BNQ_B + 2048;
static const size_t SH_B   = SC_B + 2048;

// ---------------------------------------------------------------------------
// K0: W=[wqk;wv;wt] -> wF hi/lo (fragment order)
// ---------------------------------------------------------------------------
__global__ __launch_bounds__(256) void k_wsplit(
    const float* __restrict__ wqk, const float* __restrict__ wv,
    const float* __restrict__ wt, u16* __restrict__ wh, u16* __restrict__ wl)
{
    const int idx = blockIdx.x * 256 + threadIdx.x;      // grid 576 -> exact
    const int e = idx * 4;
    const int row = e >> 9, col = e & 511;               // col multiple of 4
    const float* src = (row < 128) ? (wqk + (size_t)row * 512 + col)
                     : (row < 640) ? (wv + (size_t)(row - 128) * 512 + col)
                                   : (wt + (size_t)(row - 640) * 512 + col);
    const float4 v = *(const float4*)src;
    u16x4 h, lo;
    h[0] = f2bf(v.x); lo[0] = f2bf(v.x - bf2f(h[0]));
    h[1] = f2bf(v.y); lo[1] = f2bf(v.y - bf2f(h[1]));
    h[2] = f2bf(v.z); lo[2] = f2bf(v.z - bf2f(h[2]));
    h[3] = f2bf(v.w); lo[3] = f2bf(v.w - bf2f(h[3]));
    const int g16 = row >> 4, rl = row & 15, kk = col >> 5, dcol = col & 31;
    const size_t off = ((size_t)g16 * 16 + kk) * 512 + ((dcol >> 3) * 16 + rl) * 8 + (dcol & 7);
    *(u16x4*)(wh + off) = h;
    *(u16x4*)(wl + off) = lo;
}

// ---------------------------------------------------------------------------
// K1: transpose + split to fragment order. src [b][512][2048] f32 ->
// hi/lo [b][g16 128][kk 16] fragments (rows = n, K = c).
// ---------------------------------------------------------------------------
__global__ __launch_bounds__(256) void k_split_t(
    const float* __restrict__ src, u16* __restrict__ dsth, u16* __restrict__ dstl)
{
    __shared__ float S[64][69];
    const int b = blockIdx.z, rt = blockIdx.y, nt = blockIdx.x;
    const int tid = threadIdx.x;
    {   // load 64c x 64n f32 tile, coalesced
        const int rl = tid >> 2, c4 = (tid & 3) * 4;
        const float* sp = src + ((size_t)b * CC + rt * 64 + rl) * NN + nt * 64;
#pragma unroll
        for (int q = 0; q < 4; ++q) {
            const float4 v = *(const float4*)(sp + c4 + q * 16);
            const int col = c4 + q * 16;
            S[rl][col] = v.x; S[rl][col + 1] = v.y; S[rl][col + 2] = v.z; S[rl][col + 3] = v.w;
        }
    }
    __syncthreads();
    const int c0 = (tid & 7) * 8;               // c within tile, multiple of 8
    const int cc = rt * 64 + c0;
    const int kk = cc >> 5, dcol = cc & 31;     // dcol multiple of 8
#pragma unroll
    for (int p = 0; p < 2; ++p) {
        const int n_local = p * 32 + (tid >> 3);
        const int n = nt * 64 + n_local;
        u16x8 h, lo;
#pragma unroll
        for (int j = 0; j < 8; ++j) {
            const float v = S[c0 + j][n_local];
            const u16 hh = f2bf(v);
            h[j] = hh; lo[j] = f2bf(v - bf2f(hh));
        }
        const size_t off = (((size_t)b * 128 + (n >> 4)) * 16 + kk) * 512 +
                           ((dcol >> 3) * 16 + (n & 15)) * 8;
        *(u16x8*)(dsth + off) = h;
        *(u16x8*)(dstl + off) = lo;
    }
}

// ---------------------------------------------------------------------------
// K2: projection GEMM, split-3 bf16 MFMA, fragment-ordered operands.
// mb==0 -> xk rows (LDS transpose -> xkF fragments); mb>=1 -> xv -> xvF.
// ---------------------------------------------------------------------------
__global__ __launch_bounds__(256, 3) void k_proj_mfma(
    const u16* __restrict__ wh, const u16* __restrict__ wl,
    const u16* __restrict__ xth, const u16* __restrict__ xtl,
    const float* __restrict__ bv,
    u16* __restrict__ xkh, u16* __restrict__ xkl,
    u16* __restrict__ xvh, u16* __restrict__ xvl)
{
    __shared__ u16 Tt[128][136];
    const int b = blockIdx.z, mb = blockIdx.y, nb = blockIdx.x;
    const int tid = threadIdx.x;
    const int w = tid >> 6, l = tid & 63;
    const int l15 = l & 15, lg = l >> 4;
    const int wm = w >> 1, wn = w & 1;
    const int m0 = mb * 128 + wm * 64;
    const int n0 = nb * 128 + wn * 64;
    const u16* Bh = xth + (size_t)b * NN * CC;
    const u16* Bl = xtl + (size_t)b * NN * CC;

    f32x4 acc[4][4];
#pragma unroll
    for (int am = 0; am < 4; ++am)
#pragma unroll
        for (int an = 0; an < 4; ++an) acc[am][an] = (f32x4){0.f, 0.f, 0.f, 0.f};

    for (int kk = 0; kk < 16; ++kk) {
        s16x8 ah[4], al[4], bh4[4], bl4[4];
#pragma unroll
        for (int am = 0; am < 4; ++am) {
            const size_t fi = (size_t)(m0 / 16 + am) * 16 + kk;
            ah[am] = ldfrag(wh, fi, l);
            al[am] = ldfrag(wl, fi, l);
        }
#pragma unroll
        for (int an = 0; an < 4; ++an) {
            const size_t fi = (size_t)(n0 / 16 + an) * 16 + kk;
            bh4[an] = ldfrag(Bh, fi, l);
            bl4[an] = ldfrag(Bl, fi, l);
        }
#pragma unroll
        for (int am = 0; am < 4; ++am)
#pragma unroll
            for (int an = 0; an < 4; ++an) {
                acc[am][an] = MFMA(ah[am], bh4[an], acc[am][an]);
                acc[am][an] = MFMA(al[am], bh4[an], acc[am][an]);
                acc[am][an] = MFMA(ah[am], bl4[an], acc[am][an]);
            }
    }

    if (mb == 0) {
        // D rows are d (0..127), cols are n (128). Transpose via LDS, emit
        // xkF fragments (rows = n, K = d), hi pass then lo pass.
#pragma unroll
        for (int pass = 0; pass < 2; ++pass) {
            if (pass) __syncthreads();
#pragma unroll
            for (int am = 0; am < 4; ++am)
#pragma unroll
                for (int an = 0; an < 4; ++an) {
                    const int nl = wn * 64 + an * 16 + l15;
                    const int dbase = wm * 64 + am * 16 + lg * 4;
#pragma unroll
                    for (int r = 0; r < 4; ++r) {
                        const float v = acc[am][an][r];
                        const u16 h = f2bf(v);
                        Tt[nl][dbase + r] = pass ? f2bf(v - bf2f(h)) : h;
                    }
                }
            __syncthreads();
            u16* dst = pass ? xkl : xkh;
#pragma unroll
            for (int i = 0; i < 8; ++i) {
                const int flat = i * 256 + tid;
                const int g16l = flat >> 8;        // 0..7
                const int kk2  = (flat >> 6) & 3;  // 0..3
                const int ll   = flat & 63;
                const int row  = g16l * 16 + (ll & 15);
                const int col  = kk2 * 32 + (ll >> 4) * 8;
                const size_t fi = ((size_t)b * 128 + nb * 8 + g16l) * 4 + kk2;
                *(u16x8*)(dst + fi * 512 + ll * 8) = *(const u16x8*)&Tt[row][col];
            }
        }
    } else {
        // xv -> xvF fragments (rows = c, K = n)
#pragma unroll
        for (int am = 0; am < 4; ++am) {
            const int cb = m0 - C4 + am * 16 + lg * 4;
#pragma unroll
            for (int r = 0; r < 4; ++r) {
                const int c = cb + r;
                const float bias = bv[c];
                const int cg = c >> 4, cl = c & 15;
#pragma unroll
                for (int an = 0; an < 4; ++an) {
                    const int n = n0 + an * 16 + l15;
                    const float v = acc[am][an][r] + bias;
                    const u16 h = f2bf(v);
                    const size_t off = (((size_t)b * 64 + (n >> 5)) * 32 + cg) * 512 +
                                       (((n & 31) >> 3) * 16 + cl) * 8 + (n & 7);
                    xvh[off] = h;
                    xvl[off] = f2bf(v - bf2f(h));
                }
            }
        }
    }
}

// ---------------------------------------------------------------------------
// K3: energy pass 1 (same arithmetic; fragment loads).
// ---------------------------------------------------------------------------
__global__ __launch_bounds__(256) void k_stats(
    const u16* __restrict__ xkh, const u16* __restrict__ xkl,
    float* __restrict__ rmax, float* __restrict__ rinv)
{
    const int b = blockIdx.y, nb = blockIdx.x;
    const int tid = threadIdx.x;
    const int w = tid >> 6, l = tid & 63;
    const int l15 = l & 15, lg = l >> 4;
    const u16* Hb = xkh + (size_t)b * NN * C4;
    const u16* Lb = xkl + (size_t)b * NN * C4;
    s16x8 ah[4], al[4];
#pragma unroll
    for (int kk = 0; kk < 4; ++kk) {
        const size_t fi = (size_t)(nb * 4 + w) * 4 + kk;
        ah[kk] = ldfrag(Hb, fi, l);
        al[kk] = ldfrag(Lb, fi, l);
    }
    float m[4], s[4];
#pragma unroll
    for (int r = 0; r < 4; ++r) { m[r] = -3.0e38f; s[r] = 0.0f; }

    for (int mt = 0; mt < NN / 64; ++mt) {
        f32x4 e[4];
#pragma unroll
        for (int ms = 0; ms < 4; ++ms) e[ms] = (f32x4){0.f, 0.f, 0.f, 0.f};
#pragma unroll
        for (int kk = 0; kk < 4; ++kk) {
#pragma unroll
            for (int ms = 0; ms < 4; ++ms) {
                const size_t fi = (size_t)(mt * 4 + ms) * 4 + kk;
                const s16x8 bh = ldfrag(Hb, fi, l);
                const s16x8 bl = ldfrag(Lb, fi, l);
                e[ms] = MFMA(ah[kk], bh, e[ms]);
                e[ms] = MFMA(al[kk], bh, e[ms]);
                e[ms] = MFMA(ah[kk], bl, e[ms]);
            }
        }
#pragma unroll
        for (int r = 0; r < 4; ++r) {
            const float v0 = e[0][r], v1 = e[1][r], v2 = e[2][r], v3 = e[3][r];
            const float vm = fmaxf(fmaxf(v0, v1), fmaxf(v2, v3));
            const float nm = fmaxf(m[r], vm);
            s[r] = s[r] * __expf(m[r] - nm) +
                   __expf(v0 - nm) + __expf(v1 - nm) + __expf(v2 - nm) + __expf(v3 - nm);
            m[r] = nm;
        }
    }
#pragma unroll
    for (int off = 1; off < 16; off <<= 1) {
#pragma unroll
        for (int r = 0; r < 4; ++r) {
            const float mo = __shfl_xor(m[r], off);
            const float so = __shfl_xor(s[r], off);
            const float nm = fmaxf(m[r], mo);
            s[r] = s[r] * __expf(m[r] - nm) + so * __expf(mo - nm);
            m[r] = nm;
        }
    }
    if (l15 == 0) {
        const size_t base = (size_t)b * NN + nb * 64 + w * 16 + lg * 4;
#pragma unroll
        for (int r = 0; r < 4; ++r) {
            rmax[base + r] = m[r];
            rinv[base + r] = 1.0f / (s[r] * (1.0f + 1e-9f));
        }
    }
}

// ---------------------------------------------------------------------------
// K4: energy recompute + P + PV (same arithmetic; fragment loads).
// ---------------------------------------------------------------------------
__global__ __launch_bounds__(512, 2) void k_attn_pv(
    const u16* __restrict__ xkh, const u16* __restrict__ xkl,
    const u16* __restrict__ xvh, const u16* __restrict__ xvl,
    const float* __restrict__ x, const float* __restrict__ rmax,
    const float* __restrict__ rinv, float* __restrict__ u)
{
    __shared__ u16 pT[64][72];
    const int b = blockIdx.y, mb = blockIdx.x;
    const int tid = threadIdx.x;
    const int w = tid >> 6, l = tid & 63;
    const int l15 = l & 15, lg = l >> 4;
    const int nsub = w >> 1, jb = (w & 1) * 2;
    const int M0 = mb * 64;
    const u16* Hb = xkh + (size_t)b * NN * C4;
    const u16* Lb = xkl + (size_t)b * NN * C4;
    const u16* Vh = xvh + (size_t)b * CC * NN;
    const u16* Vl = xvl + (size_t)b * CC * NN;

    s16x8 bh[2][4], bl[2][4];
#pragma unroll
    for (int j = 0; j < 2; ++j) {
#pragma unroll
        for (int kk = 0; kk < 4; ++kk) {
            const size_t fi = (size_t)(mb * 4 + jb + j) * 4 + kk;
            bh[j][kk] = ldfrag(Hb, fi, l);
            bl[j][kk] = ldfrag(Lb, fi, l);
        }
    }
    f32x4 acc[4][4];
#pragma unroll
    for (int cs = 0; cs < 4; ++cs)
#pragma unroll
        for (int ms = 0; ms < 4; ++ms) acc[cs][ms] = (f32x4){0.f, 0.f, 0.f, 0.f};

    for (int nt = 0; nt < NN / 64; ++nt) {
        const int n0 = nt * 64;
        f32x4 e0 = {0.f, 0.f, 0.f, 0.f}, e1 = {0.f, 0.f, 0.f, 0.f};
#pragma unroll
        for (int kk = 0; kk < 4; ++kk) {
            const size_t fi = (size_t)(nt * 4 + nsub) * 4 + kk;
            const s16x8 ah = ldfrag(Hb, fi, l);
            const s16x8 al = ldfrag(Lb, fi, l);
            e0 = MFMA(ah, bh[0][kk], e0); e0 = MFMA(al, bh[0][kk], e0); e0 = MFMA(ah, bl[0][kk], e0);
            e1 = MFMA(ah, bh[1][kk], e1); e1 = MFMA(al, bh[1][kk], e1); e1 = MFMA(ah, bl[1][kk], e1);
        }
        const size_t rbase = (size_t)b * NN + n0 + nsub * 16 + lg * 4;
        const float4 rm = *(const float4*)(rmax + rbase);
        const float4 ri = *(const float4*)(rinv + rbase);
        u16x4 p0, p1;
        p0[0] = f2bf(__expf(e0[0] - rm.x) * ri.x);
        p0[1] = f2bf(__expf(e0[1] - rm.y) * ri.y);
        p0[2] = f2bf(__expf(e0[2] - rm.z) * ri.z);
        p0[3] = f2bf(__expf(e0[3] - rm.w) * ri.w);
        p1[0] = f2bf(__expf(e1[0] - rm.x) * ri.x);
        p1[1] = f2bf(__expf(e1[1] - rm.y) * ri.y);
        p1[2] = f2bf(__expf(e1[2] - rm.z) * ri.z);
        p1[3] = f2bf(__expf(e1[3] - rm.w) * ri.w);
        __syncthreads();
        const int ncol = nsub * 16 + lg * 4;
        *reinterpret_cast<u16x4*>(&pT[(jb + 0) * 16 + l15][ncol]) = p0;
        *reinterpret_cast<u16x4*>(&pT[(jb + 1) * 16 + l15][ncol]) = p1;
        __syncthreads();
#pragma unroll
        for (int kk = 0; kk < 2; ++kk) {
            const int nn = kk * 32 + lg * 8;
            s16x8 avh[4], avl[4];
#pragma unroll
            for (int cs = 0; cs < 4; ++cs) {
                const size_t fi = (size_t)(nt * 2 + kk) * 32 + (w * 4 + cs);
                avh[cs] = ldfrag(Vh, fi, l);
                avl[cs] = ldfrag(Vl, fi, l);
            }
#pragma unroll
            for (int ms = 0; ms < 4; ++ms) {
                const s16x8 bp = *reinterpret_cast<const s16x8*>(&pT[ms * 16 + l15][nn]);
#pragma unroll
                for (int cs = 0; cs < 4; ++cs) {
                    acc[cs][ms] = MFMA(avh[cs], bp, acc[cs][ms]);
                    acc[cs][ms] = MFMA(avl[cs], bp, acc[cs][ms]);
                }
            }
        }
    }
    const float* xb = x + (size_t)b * CC * NN;
    float* ub = u + (size_t)b * CC * NN;
#pragma unroll
    for (int cs = 0; cs < 4; ++cs) {
#pragma unroll
        for (int r = 0; r < 4; ++r) {
            const int c = w * 64 + cs * 16 + lg * 4 + r;
#pragma unroll
            for (int ms = 0; ms < 4; ++ms) {
                const size_t o = (size_t)c * NN + M0 + ms * 16 + l15;
                ub[o] = xb[o] - acc[cs][ms][r];
            }
        }
    }
}

// ---------------------------------------------------------------------------
// K6: t = wt@u + bt (fragment loads) + BN partial sums. W g16 base = 40.
// ---------------------------------------------------------------------------
__global__ __launch_bounds__(256, 3) void k_trans_mfma(
    const u16* __restrict__ wh, const u16* __restrict__ wl,
    const u16* __restrict__ uth, const u16* __restrict__ utl,
    const float* __restrict__ bt, float* __restrict__ t,
    float* __restrict__ bns, float* __restrict__ bnq)
{
    const int b = blockIdx.z, mb = blockIdx.y, nb = blockIdx.x;
    const int tid = threadIdx.x;
    const int w = tid >> 6, l = tid & 63;
    const int l15 = l & 15, lg = l >> 4;
    const int wm = w >> 1, wn = w & 1;
    const int m0 = mb * 128 + wm * 64;
    const int n0 = nb * 128 + wn * 64;
    const u16* Bh = uth + (size_t)b * NN * CC;
    const u16* Bl = utl + (size_t)b * NN * CC;

    f32x4 acc[4][4];
#pragma unroll
    for (int am = 0; am < 4; ++am)
#pragma unroll
        for (int an = 0; an < 4; ++an) acc[am][an] = (f32x4){0.f, 0.f, 0.f, 0.f};

    for (int kk = 0; kk < 16; ++kk) {
        s16x8 ah[4], al[4], bh4[4], bl4[4];
#pragma unroll
        for (int am = 0; am < 4; ++am) {
            const size_t fi = (size_t)(40 + m0 / 16 + am) * 16 + kk;
            ah[am] = ldfrag(wh, fi, l);
            al[am] = ldfrag(wl, fi, l);
        }
#pragma unroll
        for (int an = 0; an < 4; ++an) {
            const size_t fi = (size_t)(n0 / 16 + an) * 16 + kk;
            bh4[an] = ldfrag(Bh, fi, l);
            bl4[an] = ldfrag(Bl, fi, l);
        }
#pragma unroll
        for (int am = 0; am < 4; ++am)
#pragma unroll
            for (int an = 0; an < 4; ++an) {
                acc[am][an] = MFMA(ah[am], bh4[an], acc[am][an]);
                acc[am][an] = MFMA(al[am], bh4[an], acc[am][an]);
                acc[am][an] = MFMA(ah[am], bl4[an], acc[am][an]);
            }
    }

    float* tb = t + (size_t)b * CC * NN;
#pragma unroll
    for (int am = 0; am < 4; ++am) {
        const int cb = m0 + am * 16 + lg * 4;
        float rs[4], rq[4];
#pragma unroll
        for (int r = 0; r < 4; ++r) { rs[r] = 0.f; rq[r] = 0.f; }
#pragma unroll
        for (int r = 0; r < 4; ++r) {
            const int c = cb + r;
            const float bias = bt[c];
#pragma unroll
            for (int an = 0; an < 4; ++an) {
                const float v = acc[am][an][r] + bias;
                tb[(size_t)c * NN + n0 + an * 16 + l15] = v;
                rs[r] += v;
                rq[r] += v * v;
            }
        }
#pragma unroll
        for (int off = 1; off < 16; off <<= 1) {
#pragma unroll
            for (int r = 0; r < 4; ++r) {
                rs[r] += __shfl_xor(rs[r], off);
                rq[r] += __shfl_xor(rq[r], off);
            }
        }
        if (l15 == 0) {
#pragma unroll
            for (int r = 0; r < 4; ++r) {
                atomicAdd(&bns[cb + r], rs[r]);
                atomicAdd(&bnq[cb + r], rq[r]);
            }
        }
    }
}

// ---------------------------------------------------------------------------
__global__ void k_bnfin(const float* __restrict__ bns, const float* __restrict__ bnq,
                        const float* __restrict__ gamma, const float* __restrict__ beta,
                        float* __restrict__ scale, float* __restrict__ shift)
{
    const int c = threadIdx.x;
    if (c < CC) {
        const float inv = 1.0f / (float)(BB * NN);
        const float mean = bns[c] * inv;
        const float var = bnq[c] * inv - mean * mean;
        const float sc = gamma[c] * rsqrtf(var + 1e-5f);
        scale[c] = sc;
        shift[c] = beta[c] - mean * sc;
    }
}

__global__ __launch_bounds__(256) void k_out(
    const float* __restrict__ x, const float* __restrict__ t,
    const float* __restrict__ scale, const float* __restrict__ shift,
    float* __restrict__ out)
{
    const size_t total4 = (size_t)BB * CC * NN / 4;
    for (size_t idx = (size_t)blockIdx.x * blockDim.x + threadIdx.x; idx < total4;
         idx += (size_t)gridDim.x * blockDim.x) {
        const size_t e = idx * 4;
        const int c = (int)((e / NN) % CC);
        const float sc = scale[c], sh = shift[c];
        const float4 xq = ((const float4*)x)[idx];
        const float4 tq = ((const float4*)t)[idx];
        float4 o;
        o.x = xq.x + fmaxf(tq.x * sc + sh, 0.0f);
        o.y = xq.y + fmaxf(tq.y * sc + sh, 0.0f);
        o.z = xq.z + fmaxf(tq.z * sc + sh, 0.0f);
        o.w = xq.w + fmaxf(tq.w * sc + sh, 0.0f);
        ((float4*)out)[idx] = o;
    }
}

// ---------------------------------------------------------------------------
extern "C" void kernel_launch(void* const* d_in, const int* in_sizes, int n_in,
                              void* d_out, int out_size, void* d_ws, size_t ws_size,
                              hipStream_t stream)
{
    const float* x     = (const float*)d_in[0];
    const float* wqk   = (const float*)d_in[1];
    const float* wv    = (const float*)d_in[2];
    const float* bv    = (const float*)d_in[3];
    const float* wt    = (const float*)d_in[4];
    const float* bt    = (const float*)d_in[5];
    const float* gamma = (const float*)d_in[6];
    const float* beta  = (const float*)d_in[7];
    char* ws = (char*)d_ws;

    u16*   xkh  = (u16*)(ws + XKH_B);
    u16*   xkl  = (u16*)(ws + XKL_B);
    u16*   xvh  = (u16*)(ws + XVH_B);
    u16*   xvl  = (u16*)(ws + XVL_B);
    u16*   uth  = (u16*)(ws + XVH_B);      // overlay (xv dead after k_attn_pv)
    u16*   utl  = (u16*)(ws + XVL_B);
    u16*   xth  = (u16*)(ws + XT_B);
    u16*   xtl  = (u16*)(ws + XT_B + 33554432);
    float* ub   = (float*)(ws + XT_B);     // overlay (xT dead after k_proj_mfma)
    float* t    = (float*)(ws + XT_B);     // overlay (u dead after 2nd k_split_t)
    u16*   wh   = (u16*)(ws + W_B);
    u16*   wl   = (u16*)(ws + W_B + 1179648);
    float* rmax = (float*)(ws + RMAX_B);
    float* rinv = (float*)(ws + RINV_B);
    float* bns  = (float*)(ws + BNS_B);
    float* bnq  = (float*)(ws + BNQ_B);
    float* sc   = (float*)(ws + SC_B);
    float* sh   = (float*)(ws + SH_B);

    hipMemsetAsync(bns, 0, 2 * CC * sizeof(float), stream);  // bns+bnq contiguous

    k_wsplit<<<576, 256, 0, stream>>>(wqk, wv, wt, wh, wl);
    k_split_t<<<dim3(32, 8, BB), 256, 0, stream>>>(x, xth, xtl);
    k_proj_mfma<<<dim3(16, 5, BB), 256, 0, stream>>>(wh, wl, xth, xtl, bv,
                                                     xkh, xkl, xvh, xvl);
    k_stats<<<dim3(32, BB), 256, 0, stream>>>(xkh, xkl, rmax, rinv);
    k_attn_pv<<<dim3(32, BB), 512, 0, stream>>>(xkh, xkl, xvh, xvl, x, rmax, rinv, ub);
    k_split_t<<<dim3(32, 8, BB), 256, 0, stream>>>(ub, uth, utl);
    k_trans_mfma<<<dim3(16, 4, BB), 256, 0, stream>>>(wh, wl, uth, utl, bt, t, bns, bnq);
    k_bnfin<<<1, 512, 0, stream>>>(bns, bnq, gamma, beta, sc, sh);
    k_out<<<2048, 256, 0, stream>>>(x, t, sc, sh, (float*)d_out);
}

// Round 8
// 708.240 us; speedup vs baseline: 3.2584x; 1.0302x over previous
//
#include <hip/hip_runtime.h>

// ---------------------------------------------------------------------------
// Round 8: pipelined k_attn_pv (double-buffered pT, 1 barrier/nt, E(nt+1)
// overlapped with PV(nt)) + fused uT-fragment epilogue (second k_split_t and
// the u f32 buffer are gone).
// Fragment order (unchanged): one 16(row) x 32(K) bf16 fragment = 1KB
// contiguous; elem (row_local, d_local) at ((d_local>>3)*16+row_local)*8 +
// (d_local&7); lane l reads 16B at frag_base + l*16.
//   frag spaces: wF [72 g16][16 kk] | xtF/utF [b][128 g16][16 kk]
//                xkF [b][128 g16][4 kk] | xvF [b][64 nk][32 cg]
// ws overlays (race-checked):
//   [0, 16.8M)      xkF hi/lo            (proj -> stats, pv)
//   [16.8M, 83.9M)  xvF hi/lo (proj->pv)  -> t f32 (trans -> out)
//   [83.9M, 151M)   xT hi/lo (split->proj)-> uT hi/lo (pv epilogue -> trans)
//   [151M, 153.4M)  wF hi/lo
//   [153.4M, ...)   rmax/rinv/bns/bnq/sc/sh
// ---------------------------------------------------------------------------

#define BB 16
#define CC 512
#define C4 128
#define NN 2048

typedef unsigned short u16;
typedef __attribute__((ext_vector_type(4))) unsigned short u16x4;
typedef __attribute__((ext_vector_type(8))) unsigned short u16x8;
typedef __attribute__((ext_vector_type(8))) short s16x8;
typedef __attribute__((ext_vector_type(4))) float f32x4;

#define MFMA(a, b, c) __builtin_amdgcn_mfma_f32_16x16x32_bf16((a), (b), (c), 0, 0, 0)

static __device__ __forceinline__ u16 f2bf(float f) {  // round-to-nearest-even
    unsigned u = __float_as_uint(f);
    return (u16)((u + 0x7fffu + ((u >> 16) & 1u)) >> 16);
}
static __device__ __forceinline__ float bf2f(u16 h) {
    return __uint_as_float((unsigned)h << 16);
}
static __device__ __forceinline__ s16x8 ldfrag(const u16* __restrict__ p, size_t fi, int l) {
    return *reinterpret_cast<const s16x8*>(p + fi * 512 + l * 8);
}

// byte offsets into ws
static const size_t XKH_B  = 0;
static const size_t XKL_B  = 8388608;
static const size_t XVH_B  = 16777216;      // xvF hi -> (with XVL) t f32
static const size_t XVL_B  = 50331648;      // xvF lo
static const size_t XT_B   = 83886080;      // xT hi/lo -> uT hi/lo
static const size_t W_B    = 150994944;
static const size_t RMAX_B = 153354240;
static const size_t RINV_B = RMAX_B + 131072;
static const size_t BNS_B  = RINV_B + 131072;
static const size_t BNQ_B  = BNS_B + 2048;
static const size_t SC_B   = BNQ_B + 2048;
static const size_t SH_B   = SC_B + 2048;

// ---------------------------------------------------------------------------
// K0: W=[wqk;wv;wt] -> wF hi/lo (fragment order)
// ---------------------------------------------------------------------------
__global__ __launch_bounds__(256) void k_wsplit(
    const float* __restrict__ wqk, const float* __restrict__ wv,
    const float* __restrict__ wt, u16* __restrict__ wh, u16* __restrict__ wl)
{
    const int idx = blockIdx.x * 256 + threadIdx.x;      // grid 576 -> exact
    const int e = idx * 4;
    const int row = e >> 9, col = e & 511;
    const float* src = (row < 128) ? (wqk + (size_t)row * 512 + col)
                     : (row < 640) ? (wv + (size_t)(row - 128) * 512 + col)
                                   : (wt + (size_t)(row - 640) * 512 + col);
    const float4 v = *(const float4*)src;
    u16x4 h, lo;
    h[0] = f2bf(v.x); lo[0] = f2bf(v.x - bf2f(h[0]));
    h[1] = f2bf(v.y); lo[1] = f2bf(v.y - bf2f(h[1]));
    h[2] = f2bf(v.z); lo[2] = f2bf(v.z - bf2f(h[2]));
    h[3] = f2bf(v.w); lo[3] = f2bf(v.w - bf2f(h[3]));
    const int g16 = row >> 4, rl = row & 15, kk = col >> 5, dcol = col & 31;
    const size_t off = ((size_t)g16 * 16 + kk) * 512 + ((dcol >> 3) * 16 + rl) * 8 + (dcol & 7);
    *(u16x4*)(wh + off) = h;
    *(u16x4*)(wl + off) = lo;
}

// ---------------------------------------------------------------------------
// K1: transpose + split to fragment order. src [b][512][2048] f32 ->
// hi/lo [b][g16 128][kk 16] fragments (rows = n, K = c).
// ---------------------------------------------------------------------------
__global__ __launch_bounds__(256) void k_split_t(
    const float* __restrict__ src, u16* __restrict__ dsth, u16* __restrict__ dstl)
{
    __shared__ float S[64][69];
    const int b = blockIdx.z, rt = blockIdx.y, nt = blockIdx.x;
    const int tid = threadIdx.x;
    {
        const int rl = tid >> 2, c4 = (tid & 3) * 4;
        const float* sp = src + ((size_t)b * CC + rt * 64 + rl) * NN + nt * 64;
#pragma unroll
        for (int q = 0; q < 4; ++q) {
            const float4 v = *(const float4*)(sp + c4 + q * 16);
            const int col = c4 + q * 16;
            S[rl][col] = v.x; S[rl][col + 1] = v.y; S[rl][col + 2] = v.z; S[rl][col + 3] = v.w;
        }
    }
    __syncthreads();
    const int c0 = (tid & 7) * 8;
    const int cc = rt * 64 + c0;
    const int kk = cc >> 5, dcol = cc & 31;
#pragma unroll
    for (int p = 0; p < 2; ++p) {
        const int n_local = p * 32 + (tid >> 3);
        const int n = nt * 64 + n_local;
        u16x8 h, lo;
#pragma unroll
        for (int j = 0; j < 8; ++j) {
            const float v = S[c0 + j][n_local];
            const u16 hh = f2bf(v);
            h[j] = hh; lo[j] = f2bf(v - bf2f(hh));
        }
        const size_t off = (((size_t)b * 128 + (n >> 4)) * 16 + kk) * 512 +
                           ((dcol >> 3) * 16 + (n & 15)) * 8;
        *(u16x8*)(dsth + off) = h;
        *(u16x8*)(dstl + off) = lo;
    }
}

// ---------------------------------------------------------------------------
// K2: projection GEMM (unchanged from round 7).
// ---------------------------------------------------------------------------
__global__ __launch_bounds__(256, 3) void k_proj_mfma(
    const u16* __restrict__ wh, const u16* __restrict__ wl,
    const u16* __restrict__ xth, const u16* __restrict__ xtl,
    const float* __restrict__ bv,
    u16* __restrict__ xkh, u16* __restrict__ xkl,
    u16* __restrict__ xvh, u16* __restrict__ xvl)
{
    __shared__ u16 Tt[128][136];
    const int b = blockIdx.z, mb = blockIdx.y, nb = blockIdx.x;
    const int tid = threadIdx.x;
    const int w = tid >> 6, l = tid & 63;
    const int l15 = l & 15, lg = l >> 4;
    const int wm = w >> 1, wn = w & 1;
    const int m0 = mb * 128 + wm * 64;
    const int n0 = nb * 128 + wn * 64;
    const u16* Bh = xth + (size_t)b * NN * CC;
    const u16* Bl = xtl + (size_t)b * NN * CC;

    f32x4 acc[4][4];
#pragma unroll
    for (int am = 0; am < 4; ++am)
#pragma unroll
        for (int an = 0; an < 4; ++an) acc[am][an] = (f32x4){0.f, 0.f, 0.f, 0.f};

    for (int kk = 0; kk < 16; ++kk) {
        s16x8 ah[4], al[4], bh4[4], bl4[4];
#pragma unroll
        for (int am = 0; am < 4; ++am) {
            const size_t fi = (size_t)(m0 / 16 + am) * 16 + kk;
            ah[am] = ldfrag(wh, fi, l);
            al[am] = ldfrag(wl, fi, l);
        }
#pragma unroll
        for (int an = 0; an < 4; ++an) {
            const size_t fi = (size_t)(n0 / 16 + an) * 16 + kk;
            bh4[an] = ldfrag(Bh, fi, l);
            bl4[an] = ldfrag(Bl, fi, l);
        }
#pragma unroll
        for (int am = 0; am < 4; ++am)
#pragma unroll
            for (int an = 0; an < 4; ++an) {
                acc[am][an] = MFMA(ah[am], bh4[an], acc[am][an]);
                acc[am][an] = MFMA(al[am], bh4[an], acc[am][an]);
                acc[am][an] = MFMA(ah[am], bl4[an], acc[am][an]);
            }
    }

    if (mb == 0) {
#pragma unroll
        for (int pass = 0; pass < 2; ++pass) {
            if (pass) __syncthreads();
#pragma unroll
            for (int am = 0; am < 4; ++am)
#pragma unroll
                for (int an = 0; an < 4; ++an) {
                    const int nl = wn * 64 + an * 16 + l15;
                    const int dbase = wm * 64 + am * 16 + lg * 4;
#pragma unroll
                    for (int r = 0; r < 4; ++r) {
                        const float v = acc[am][an][r];
                        const u16 h = f2bf(v);
                        Tt[nl][dbase + r] = pass ? f2bf(v - bf2f(h)) : h;
                    }
                }
            __syncthreads();
            u16* dst = pass ? xkl : xkh;
#pragma unroll
            for (int i = 0; i < 8; ++i) {
                const int flat = i * 256 + tid;
                const int g16l = flat >> 8;
                const int kk2  = (flat >> 6) & 3;
                const int ll   = flat & 63;
                const int row  = g16l * 16 + (ll & 15);
                const int col  = kk2 * 32 + (ll >> 4) * 8;
                const size_t fi = ((size_t)b * 128 + nb * 8 + g16l) * 4 + kk2;
                *(u16x8*)(dst + fi * 512 + ll * 8) = *(const u16x8*)&Tt[row][col];
            }
        }
    } else {
#pragma unroll
        for (int am = 0; am < 4; ++am) {
            const int cb = m0 - C4 + am * 16 + lg * 4;
#pragma unroll
            for (int r = 0; r < 4; ++r) {
                const int c = cb + r;
                const float bias = bv[c];
                const int cg = c >> 4, cl = c & 15;
#pragma unroll
                for (int an = 0; an < 4; ++an) {
                    const int n = n0 + an * 16 + l15;
                    const float v = acc[am][an][r] + bias;
                    const u16 h = f2bf(v);
                    const size_t off = (((size_t)b * 64 + (n >> 5)) * 32 + cg) * 512 +
                                       (((n & 31) >> 3) * 16 + cl) * 8 + (n & 7);
                    xvh[off] = h;
                    xvl[off] = f2bf(v - bf2f(h));
                }
            }
        }
    }
}

// ---------------------------------------------------------------------------
// K3: energy pass 1 (unchanged from round 7, validated).
// ---------------------------------------------------------------------------
__global__ __launch_bounds__(256) void k_stats(
    const u16* __restrict__ xkh, const u16* __restrict__ xkl,
    float* __restrict__ rmax, float* __restrict__ rinv)
{
    const int b = blockIdx.y, nb = blockIdx.x;
    const int tid = threadIdx.x;
    const int w = tid >> 6, l = tid & 63;
    const int l15 = l & 15, lg = l >> 4;
    const u16* Hb = xkh + (size_t)b * NN * C4;
    const u16* Lb = xkl + (size_t)b * NN * C4;
    s16x8 ah[4], al[4];
#pragma unroll
    for (int kk = 0; kk < 4; ++kk) {
        const size_t fi = (size_t)(nb * 4 + w) * 4 + kk;
        ah[kk] = ldfrag(Hb, fi, l);
        al[kk] = ldfrag(Lb, fi, l);
    }
    float m[4], s[4];
#pragma unroll
    for (int r = 0; r < 4; ++r) { m[r] = -3.0e38f; s[r] = 0.0f; }

    for (int mt = 0; mt < NN / 64; ++mt) {
        f32x4 e[4];
#pragma unroll
        for (int ms = 0; ms < 4; ++ms) e[ms] = (f32x4){0.f, 0.f, 0.f, 0.f};
#pragma unroll
        for (int kk = 0; kk < 4; ++kk) {
#pragma unroll
            for (int ms = 0; ms < 4; ++ms) {
                const size_t fi = (size_t)(mt * 4 + ms) * 4 + kk;
                const s16x8 bh = ldfrag(Hb, fi, l);
                const s16x8 bl = ldfrag(Lb, fi, l);
                e[ms] = MFMA(ah[kk], bh, e[ms]);
                e[ms] = MFMA(al[kk], bh, e[ms]);
                e[ms] = MFMA(ah[kk], bl, e[ms]);
            }
        }
#pragma unroll
        for (int r = 0; r < 4; ++r) {
            const float v0 = e[0][r], v1 = e[1][r], v2 = e[2][r], v3 = e[3][r];
            const float vm = fmaxf(fmaxf(v0, v1), fmaxf(v2, v3));
            const float nm = fmaxf(m[r], vm);
            s[r] = s[r] * __expf(m[r] - nm) +
                   __expf(v0 - nm) + __expf(v1 - nm) + __expf(v2 - nm) + __expf(v3 - nm);
            m[r] = nm;
        }
    }
#pragma unroll
    for (int off = 1; off < 16; off <<= 1) {
#pragma unroll
        for (int r = 0; r < 4; ++r) {
            const float mo = __shfl_xor(m[r], off);
            const float so = __shfl_xor(s[r], off);
            const float nm = fmaxf(m[r], mo);
            s[r] = s[r] * __expf(m[r] - nm) + so * __expf(mo - nm);
            m[r] = nm;
        }
    }
    if (l15 == 0) {
        const size_t base = (size_t)b * NN + nb * 64 + w * 16 + lg * 4;
#pragma unroll
        for (int r = 0; r < 4; ++r) {
            rmax[base + r] = m[r];
            rinv[base + r] = 1.0f / (s[r] * (1.0f + 1e-9f));
        }
    }
}

// ---------------------------------------------------------------------------
// K4: pipelined E/PV. Double-buffered pT, one barrier per nt. Epilogue emits
// uT hi/lo fragments directly (u = x - x_r), to the dead xT region.
// ---------------------------------------------------------------------------
__global__ __launch_bounds__(512, 2) void k_attn_pv(
    const u16* __restrict__ xkh, const u16* __restrict__ xkl,
    const u16* __restrict__ xvh, const u16* __restrict__ xvl,
    const float* __restrict__ x, const float* __restrict__ rmax,
    const float* __restrict__ rinv,
    u16* __restrict__ uth, u16* __restrict__ utl)
{
    __shared__ u16 pT[2][64][72];
    const int b = blockIdx.y, mb = blockIdx.x;
    const int tid = threadIdx.x;
    const int w = tid >> 6, l = tid & 63;
    const int l15 = l & 15, lg = l >> 4;
    const int nsub = w >> 1, jb = (w & 1) * 2;
    const int M0 = mb * 64;
    const u16* Hb = xkh + (size_t)b * NN * C4;
    const u16* Lb = xkl + (size_t)b * NN * C4;
    const u16* Vh = xvh + (size_t)b * CC * NN;
    const u16* Vl = xvl + (size_t)b * CC * NN;

    s16x8 bh[2][4], bl[2][4];
#pragma unroll
    for (int j = 0; j < 2; ++j) {
#pragma unroll
        for (int kk = 0; kk < 4; ++kk) {
            const size_t fi = (size_t)(mb * 4 + jb + j) * 4 + kk;
            bh[j][kk] = ldfrag(Hb, fi, l);
            bl[j][kk] = ldfrag(Lb, fi, l);
        }
    }

    // E for tile nt -> e0 (rows jb+0), e1 (rows jb+1). Same split/order as k_stats.
    auto computeE = [&](int nt, f32x4& E0, f32x4& E1) {
        E0 = (f32x4){0.f, 0.f, 0.f, 0.f};
        E1 = (f32x4){0.f, 0.f, 0.f, 0.f};
#pragma unroll
        for (int kk = 0; kk < 4; ++kk) {
            const size_t fi = (size_t)(nt * 4 + nsub) * 4 + kk;
            const s16x8 ah = ldfrag(Hb, fi, l);
            const s16x8 al = ldfrag(Lb, fi, l);
            E0 = MFMA(ah, bh[0][kk], E0); E0 = MFMA(al, bh[0][kk], E0); E0 = MFMA(ah, bl[0][kk], E0);
            E1 = MFMA(ah, bh[1][kk], E1); E1 = MFMA(al, bh[1][kk], E1); E1 = MFMA(ah, bl[1][kk], E1);
        }
    };
    // softmax + write P^T into pT[nt&1]
    auto softmaxWrite = [&](int nt, f32x4 E0, f32x4 E1) {
        const size_t rbase = (size_t)b * NN + nt * 64 + nsub * 16 + lg * 4;
        const float4 rm = *(const float4*)(rmax + rbase);
        const float4 ri = *(const float4*)(rinv + rbase);
        u16x4 p0, p1;
        p0[0] = f2bf(__expf(E0[0] - rm.x) * ri.x);
        p0[1] = f2bf(__expf(E0[1] - rm.y) * ri.y);
        p0[2] = f2bf(__expf(E0[2] - rm.z) * ri.z);
        p0[3] = f2bf(__expf(E0[3] - rm.w) * ri.w);
        p1[0] = f2bf(__expf(E1[0] - rm.x) * ri.x);
        p1[1] = f2bf(__expf(E1[1] - rm.y) * ri.y);
        p1[2] = f2bf(__expf(E1[2] - rm.z) * ri.z);
        p1[3] = f2bf(__expf(E1[3] - rm.w) * ri.w);
        const int buf = nt & 1;
        const int ncol = nsub * 16 + lg * 4;
        *reinterpret_cast<u16x4*>(&pT[buf][(jb + 0) * 16 + l15][ncol]) = p0;
        *reinterpret_cast<u16x4*>(&pT[buf][(jb + 1) * 16 + l15][ncol]) = p1;
    };

    f32x4 acc[4][4];
#pragma unroll
    for (int cs = 0; cs < 4; ++cs)
#pragma unroll
        for (int ms = 0; ms < 4; ++ms) acc[cs][ms] = (f32x4){0.f, 0.f, 0.f, 0.f};

    {   // prologue: fill pT[0]
        f32x4 e0, e1;
        computeE(0, e0, e1);
        softmaxWrite(0, e0, e1);
    }
    __syncthreads();

    for (int nt = 0; nt < NN / 64; ++nt) {
        const int n0 = nt * 64;
        const int buf = nt & 1;
        const bool more = (nt + 1) < NN / 64;
        f32x4 ne0, ne1;
        if (more) computeE(nt + 1, ne0, ne1);   // overlaps PV below in the pipe
        // ---- PV(nt): acc += xv(hi,lo) @ P ----
#pragma unroll
        for (int kk = 0; kk < 2; ++kk) {
            const int nn = kk * 32 + lg * 8;
            s16x8 avh[4], avl[4];
#pragma unroll
            for (int cs = 0; cs < 4; ++cs) {
                const size_t fi = (size_t)(nt * 2 + kk) * 32 + (w * 4 + cs);
                avh[cs] = ldfrag(Vh, fi, l);
                avl[cs] = ldfrag(Vl, fi, l);
            }
#pragma unroll
            for (int ms = 0; ms < 4; ++ms) {
                const s16x8 bp = *reinterpret_cast<const s16x8*>(&pT[buf][ms * 16 + l15][nn]);
#pragma unroll
                for (int cs = 0; cs < 4; ++cs) {
                    acc[cs][ms] = MFMA(avh[cs], bp, acc[cs][ms]);
                    acc[cs][ms] = MFMA(avl[cs], bp, acc[cs][ms]);
                }
            }
        }
        if (more) softmaxWrite(nt + 1, ne0, ne1);
        __syncthreads();   // writes of pT[(nt+1)&1] visible; PV(nt) readers done
    }

    // ---- epilogue: uT = split(x - x_r) as fragments (rows = n, K = c) ----
    const float* xb = x + (size_t)b * CC * NN;
#pragma unroll
    for (int cs = 0; cs < 4; ++cs) {
#pragma unroll
        for (int r = 0; r < 4; ++r) {
            const int c = w * 64 + cs * 16 + lg * 4 + r;
#pragma unroll
            for (int ms = 0; ms < 4; ++ms) {
                const int n = M0 + ms * 16 + l15;
                const float v = xb[(size_t)c * NN + n] - acc[cs][ms][r];
                const u16 h = f2bf(v);
                const size_t off = (((size_t)b * 128 + (n >> 4)) * 16 + (c >> 5)) * 512 +
                                   (((c & 31) >> 3) * 16 + (n & 15)) * 8 + (c & 7);
                uth[off] = h;
                utl[off] = f2bf(v - bf2f(h));
            }
        }
    }
}

// ---------------------------------------------------------------------------
// K6: t = wt@u + bt (fragment loads) + BN partial sums. W g16 base = 40.
// ---------------------------------------------------------------------------
__global__ __launch_bounds__(256, 3) void k_trans_mfma(
    const u16* __restrict__ wh, const u16* __restrict__ wl,
    const u16* __restrict__ uth, const u16* __restrict__ utl,
    const float* __restrict__ bt, float* __restrict__ t,
    float* __restrict__ bns, float* __restrict__ bnq)
{
    const int b = blockIdx.z, mb = blockIdx.y, nb = blockIdx.x;
    const int tid = threadIdx.x;
    const int w = tid >> 6, l = tid & 63;
    const int l15 = l & 15, lg = l >> 4;
    const int wm = w >> 1, wn = w & 1;
    const int m0 = mb * 128 + wm * 64;
    const int n0 = nb * 128 + wn * 64;
    const u16* Bh = uth + (size_t)b * NN * CC;
    const u16* Bl = utl + (size_t)b * NN * CC;

    f32x4 acc[4][4];
#pragma unroll
    for (int am = 0; am < 4; ++am)
#pragma unroll
        for (int an = 0; an < 4; ++an) acc[am][an] = (f32x4){0.f, 0.f, 0.f, 0.f};

    for (int kk = 0; kk < 16; ++kk) {
        s16x8 ah[4], al[4], bh4[4], bl4[4];
#pragma unroll
        for (int am = 0; am < 4; ++am) {
            const size_t fi = (size_t)(40 + m0 / 16 + am) * 16 + kk;
            ah[am] = ldfrag(wh, fi, l);
            al[am] = ldfrag(wl, fi, l);
        }
#pragma unroll
        for (int an = 0; an < 4; ++an) {
            const size_t fi = (size_t)(n0 / 16 + an) * 16 + kk;
            bh4[an] = ldfrag(Bh, fi, l);
            bl4[an] = ldfrag(Bl, fi, l);
        }
#pragma unroll
        for (int am = 0; am < 4; ++am)
#pragma unroll
            for (int an = 0; an < 4; ++an) {
                acc[am][an] = MFMA(ah[am], bh4[an], acc[am][an]);
                acc[am][an] = MFMA(al[am], bh4[an], acc[am][an]);
                acc[am][an] = MFMA(ah[am], bl4[an], acc[am][an]);
            }
    }

    float* tb = t + (size_t)b * CC * NN;
#pragma unroll
    for (int am = 0; am < 4; ++am) {
        const int cb = m0 + am * 16 + lg * 4;
        float rs[4], rq[4];
#pragma unroll
        for (int r = 0; r < 4; ++r) { rs[r] = 0.f; rq[r] = 0.f; }
#pragma unroll
        for (int r = 0; r < 4; ++r) {
            const int c = cb + r;
            const float bias = bt[c];
#pragma unroll
            for (int an = 0; an < 4; ++an) {
                const float v = acc[am][an][r] + bias;
                tb[(size_t)c * NN + n0 + an * 16 + l15] = v;
                rs[r] += v;
                rq[r] += v * v;
            }
        }
#pragma unroll
        for (int off = 1; off < 16; off <<= 1) {
#pragma unroll
            for (int r = 0; r < 4; ++r) {
                rs[r] += __shfl_xor(rs[r], off);
                rq[r] += __shfl_xor(rq[r], off);
            }
        }
        if (l15 == 0) {
#pragma unroll
            for (int r = 0; r < 4; ++r) {
                atomicAdd(&bns[cb + r], rs[r]);
                atomicAdd(&bnq[cb + r], rq[r]);
            }
        }
    }
}

// ---------------------------------------------------------------------------
__global__ void k_bnfin(const float* __restrict__ bns, const float* __restrict__ bnq,
                        const float* __restrict__ gamma, const float* __restrict__ beta,
                        float* __restrict__ scale, float* __restrict__ shift)
{
    const int c = threadIdx.x;
    if (c < CC) {
        const float inv = 1.0f / (float)(BB * NN);
        const float mean = bns[c] * inv;
        const float var = bnq[c] * inv - mean * mean;
        const float sc = gamma[c] * rsqrtf(var + 1e-5f);
        scale[c] = sc;
        shift[c] = beta[c] - mean * sc;
    }
}

__global__ __launch_bounds__(256) void k_out(
    const float* __restrict__ x, const float* __restrict__ t,
    const float* __restrict__ scale, const float* __restrict__ shift,
    float* __restrict__ out)
{
    const size_t total4 = (size_t)BB * CC * NN / 4;
    for (size_t idx = (size_t)blockIdx.x * blockDim.x + threadIdx.x; idx < total4;
         idx += (size_t)gridDim.x * blockDim.x) {
        const size_t e = idx * 4;
        const int c = (int)((e / NN) % CC);
        const float sc = scale[c], sh = shift[c];
        const float4 xq = ((const float4*)x)[idx];
        const float4 tq = ((const float4*)t)[idx];
        float4 o;
        o.x = xq.x + fmaxf(tq.x * sc + sh, 0.0f);
        o.y = xq.y + fmaxf(tq.y * sc + sh, 0.0f);
        o.z = xq.z + fmaxf(tq.z * sc + sh, 0.0f);
        o.w = xq.w + fmaxf(tq.w * sc + sh, 0.0f);
        ((float4*)out)[idx] = o;
    }
}

// ---------------------------------------------------------------------------
extern "C" void kernel_launch(void* const* d_in, const int* in_sizes, int n_in,
                              void* d_out, int out_size, void* d_ws, size_t ws_size,
                              hipStream_t stream)
{
    const float* x     = (const float*)d_in[0];
    const float* wqk   = (const float*)d_in[1];
    const float* wv    = (const float*)d_in[2];
    const float* bv    = (const float*)d_in[3];
    const float* wt    = (const float*)d_in[4];
    const float* bt    = (const float*)d_in[5];
    const float* gamma = (const float*)d_in[6];
    const float* beta  = (const float*)d_in[7];
    char* ws = (char*)d_ws;

    u16*   xkh  = (u16*)(ws + XKH_B);
    u16*   xkl  = (u16*)(ws + XKL_B);
    u16*   xvh  = (u16*)(ws + XVH_B);
    u16*   xvl  = (u16*)(ws + XVL_B);
    u16*   xth  = (u16*)(ws + XT_B);
    u16*   xtl  = (u16*)(ws + XT_B + 33554432);
    u16*   uth  = (u16*)(ws + XT_B);            // overlay: xT dead after proj
    u16*   utl  = (u16*)(ws + XT_B + 33554432);
    float* t    = (float*)(ws + XVH_B);         // overlay: xv dead after pv
    u16*   wh   = (u16*)(ws + W_B);
    u16*   wl   = (u16*)(ws + W_B + 1179648);
    float* rmax = (float*)(ws + RMAX_B);
    float* rinv = (float*)(ws + RINV_B);
    float* bns  = (float*)(ws + BNS_B);
    float* bnq  = (float*)(ws + BNQ_B);
    float* sc   = (float*)(ws + SC_B);
    float* sh   = (float*)(ws + SH_B);

    hipMemsetAsync(bns, 0, 2 * CC * sizeof(float), stream);  // bns+bnq contiguous

    k_wsplit<<<576, 256, 0, stream>>>(wqk, wv, wt, wh, wl);
    k_split_t<<<dim3(32, 8, BB), 256, 0, stream>>>(x, xth, xtl);
    k_proj_mfma<<<dim3(16, 5, BB), 256, 0, stream>>>(wh, wl, xth, xtl, bv,
                                                     xkh, xkl, xvh, xvl);
    k_stats<<<dim3(32, BB), 256, 0, stream>>>(xkh, xkl, rmax, rinv);
    k_attn_pv<<<dim3(32, BB), 512, 0, stream>>>(xkh, xkl, xvh, xvl, x, rmax, rinv,
                                                uth, utl);
    k_trans_mfma<<<dim3(16, 4, BB), 256, 0, stream>>>(wh, wl, uth, utl, bt, t, bns, bnq);
    k_bnfin<<<1, 512, 0, stream>>>(bns, bnq, gamma, beta, sc, sh);
    k_out<<<2048, 256, 0, stream>>>(x, t, sc, sh, (float*)d_out);
}